// Round 11
// baseline (605.473 us; speedup 1.0000x reference)
//
#include <hip/hip_runtime.h>
#include <hip/hip_bf16.h>
#include <stdint.h>

typedef __bf16 bf16_t;
typedef bf16_t bf16x8 __attribute__((ext_vector_type(8)));
typedef bf16_t bf16x2 __attribute__((ext_vector_type(2)));
typedef float f32x4 __attribute__((ext_vector_type(4)));

#define E_N 65536
#define T_N 262144
#define CAP 16          // bucket capacity per edge (avg occupancy 4)
#define OVF_MAX T_N     // overflow list can hold every triplet -> always correct
#define EINV 0x7fffffff

__device__ __forceinline__ float silu_f(float v) {
  return v / (1.0f + __expf(-v));
}

// B-row permutation: LDS row r = tj*16+i holds real output column
// 32*(tj>>1) + 2*i + (tj&1), so each lane's acc[2g],acc[2g+1] are 2
// consecutive real columns -> bf16x2 stores everywhere.
__device__ __forceinline__ int permrow(int n) {
  return (n & ~31) | ((n & 1) << 4) | ((n & 30) >> 1);
}

__device__ __forceinline__ uint32_t pack_bf16(float a, float b) {
  union { bf16x2 h; uint32_t u; } u;
  u.h[0] = (bf16_t)a; u.h[1] = (bf16_t)b;
  return u.u;
}

// ---- async global->LDS DMA (16B per lane; LDS dst = uniform base + lane*16) ----
__device__ __forceinline__ void g2l16(const void* g, void* l) {
  __builtin_amdgcn_global_load_lds(
      (const __attribute__((address_space(1))) void*)g,
      (__attribute__((address_space(3))) void*)l, 16, 0, 0);
}

// ---- MFMA tile GEMM on swizzled stride-128 LDS tiles ----
// element (row,k) stored at row*128 + (((k>>3) ^ (row&15))<<3) + (k&7)
template<int KI, int NTJ>
__device__ __forceinline__ void gemm_tile(const bf16_t* A, const bf16_t* B,
                                          int mb, int nb, int l16, int q,
                                          f32x4 (&acc)[2][NTJ]) {
#pragma unroll
  for (int kt = 0; kt < KI; ++kt) {
    const int sw = ((kt * 4 + q) ^ l16) << 3;
    bf16x8 a0 = *(const bf16x8*)(A + ((mb + l16) << 7) + sw);
    bf16x8 a1 = *(const bf16x8*)(A + ((mb + 16 + l16) << 7) + sw);
#pragma unroll
    for (int tj = 0; tj < NTJ; ++tj) {
      bf16x8 b = *(const bf16x8*)(B + ((nb + tj * 16 + l16) << 7) + sw);
      acc[0][tj] = __builtin_amdgcn_mfma_f32_16x16x32_bf16(a0, b, acc[0][tj], 0, 0, 0);
      acc[1][tj] = __builtin_amdgcn_mfma_f32_16x16x32_bf16(a1, b, acc[1][tj], 0, 0, 0);
    }
  }
}

// Stage fp32 [64][K] tile -> swizzled bf16 LDS. C4 = K/4.
template<int C4>
__device__ __forceinline__ void stage_x(bf16_t* dst, const float* src, int tid) {
  const float4* g = (const float4*)src;
#pragma unroll
  for (int i = tid; i < 64 * C4; i += 256) {
    const int row = i / C4, c4 = i % C4;
    float4 v = g[i];
    bf16_t t[4] = {(bf16_t)v.x, (bf16_t)v.y, (bf16_t)v.z, (bf16_t)v.w};
    *(uint2*)(dst + (row << 7) + ((((c4 >> 1) ^ (row & 15)) << 3) | ((c4 & 1) << 2))) =
        *(const uint2*)t;
  }
}

// =====================  K0: fused preprocessing + triplet c8 + bt-buckets  ========
// blocks 0..4095: c8 projection + CSR bucket build.
// blocks 4096..5234: weight LDS-images, wcb fusion, swizzled x-tile images.
// blocks 5235..5490: bt-bucket build (edges with bt<4 -> btlist[bt]).
__global__ __launch_bounds__(256, 4)
void prep_c8_kernel(
    const float* __restrict__ W_ji, const float* __restrict__ W_kj,
    const float* __restrict__ W_down, const float* __restrict__ W_up,
    const float* __restrict__ rb1, const float* __restrict__ rb2,
    const float* __restrict__ W_lin, const float* __restrict__ ra1,
    const float* __restrict__ ra2, const float* __restrict__ W_rbf1,
    const float* __restrict__ W_rbf2, const float* __restrict__ x,
    char* __restrict__ wm_img, char* __restrict__ wdn_img,
    char* __restrict__ pset, bf16_t* __restrict__ wcb,
    bf16_t* __restrict__ ximg,
    const float* __restrict__ sbf, const int* __restrict__ idx_kj,
    const int* __restrict__ idx_ji, const int* __restrict__ bt,
    const float* __restrict__ Wsbf1,
    float* __restrict__ c8g, uint32_t* __restrict__ meta,
    int* __restrict__ cnt, int* __restrict__ list,
    int* __restrict__ ovf, int* __restrict__ btlist, int* __restrict__ bcnt)
{
  __shared__ __align__(16) union {
    bf16_t tile[64 * 128];        // prep x-image path (16 KB)
    struct {                      // c8 path (~23.7 KB)
      float s_sbf[64 * 44];
      float s_W1[2016];           // [6][42][8]
      float s_c8[64 * 16];
      int s_bs[64];
    } c;
  } S;

  const int tid = threadIdx.x;
  const int blk = blockIdx.x;

  if (blk < 4096) {
    // ==================== c8 path ====================
    const int base = blk * 64;

    for (int i = tid; i < 2016; i += 256) S.c.s_W1[i] = Wsbf1[i];
    if (tid < 64) {
      const int t = base + tid;
      const int kj = idx_kj[t];
      const int ji = idx_ji[t];
      const int bs = bt[kj] + 1;   // BT_LIST[b] = b-1 for b>=1; bt in [0,5)
      S.c.s_bs[tid] = bs;
      meta[t] = (uint32_t)kj | ((uint32_t)bs << 16);
      const int pos = atomicAdd(&cnt[ji], 1);
      if (pos < CAP) {
        list[ji * CAP + pos] = t;
      } else {
        const int o = atomicAdd(&ovf[0], 1);
        if (o < OVF_MAX) { ovf[2 + 2 * o] = t; ovf[2 + 2 * o + 1] = ji; }
      }
    }
    {
      const float2* sg = (const float2*)(sbf + (size_t)base * 42);
      for (int i = tid; i < 64 * 21; i += 256) {
        const int r = i / 21, c2 = i - r * 21;
        const float2 v = sg[i];
        S.c.s_sbf[r * 44 + c2 * 2] = v.x;
        S.c.s_sbf[r * 44 + c2 * 2 + 1] = v.y;
      }
    }
    __syncthreads();

    { // c8[i][brr*8+c] : brr=0 -> branch 5, brr=1 -> branch bs
      const int i = tid >> 2;
      const int brr = (tid >> 1) & 1;
      const int cg = tid & 1;
      const int b = brr ? S.c.s_bs[i] : 5;
      const float* w = &S.c.s_W1[b * 336 + cg * 4];
      const float* sb = &S.c.s_sbf[i * 44];
      float a0 = 0.f, a1 = 0.f, a2 = 0.f, a3 = 0.f;
#pragma unroll
      for (int s = 0; s < 42; ++s) {
        const float sv = sb[s];
        const float* ws = w + s * 8;
        a0 += sv * ws[0]; a1 += sv * ws[1]; a2 += sv * ws[2]; a3 += sv * ws[3];
      }
      float* dc = &S.c.s_c8[i * 16 + brr * 8 + cg * 4];
      dc[0] = a0; dc[1] = a1; dc[2] = a2; dc[3] = a3;
    }
    __syncthreads();

    { // coalesced write-out: 256 threads x float4 = 64 triplets x 16 floats
      const float4* s4 = (const float4*)S.c.s_c8;
      float4* g4 = (float4*)(c8g + (size_t)base * 16);
      g4[tid] = s4[tid];
    }
    return;
  }
  if (blk >= 5235) {
    // ==================== bt-bucket build ====================
    const int e = (blk - 5235) * 256 + tid;
    const int bte = bt[e];
    if (bte < 4) {    // bt==4 -> branch 5, covered by down5
      const int pos = atomicAdd(&bcnt[bte], 1);
      btlist[bte * E_N + pos] = e;
    }
    return;
  }

  // ==================== prep path ====================
  const int pblk = blk - 4096;
  if (pblk >= 115) {       // x tile image: stage to LDS then dump linearly
    const int t = pblk - 115;    // 0..1023
    stage_x<32>(S.tile, x + (size_t)t * 8192, tid);
    __syncthreads();
    uint4* dst = (uint4*)(ximg + (size_t)t * 8192);
    const uint4* s = (const uint4*)S.tile;
#pragma unroll
    for (int i = 0; i < 4; ++i) dst[i * 256 + tid] = s[i * 256 + tid];
    return;
  }
  if (pblk >= 112) {       // fused W_rbf1@W_rbf2 -> wcb plain [5][128][8]
    const int o = (pblk - 112) * 256 + tid;
    if (o < 640) {
      const int b = o >> 7, n = o & 127;
      bf16_t t[8];
#pragma unroll
      for (int r = 0; r < 6; ++r) {
        const float* w1 = W_rbf1 + (b + 1) * 48 + r * 8;
        const float* w2 = W_rbf2 + (b + 1) * 1024 + n;
        float s = 0.f;
#pragma unroll
        for (int c = 0; c < 8; ++c) s += w1[c] * w2[c * 128];
        t[r] = (bf16_t)s;
      }
      t[6] = (bf16_t)0.f; t[7] = (bf16_t)0.f;
      *(uint4*)(wcb + (b * 128 + n) * 8) = *(const uint4*)t;
    }
    return;
  }
  if (pblk >= 108) {       // Wup [128 rows, k8<8] image -> pset slot 0
    const int item = (pblk - 108) * 256 + tid;
    const int n = item >> 3, k8 = item & 7;
    bf16_t t[8];
#pragma unroll
    for (int j = 0; j < 8; ++j) t[j] = (bf16_t)W_up[(k8 * 8 + j) * 128 + n];
    const int row = permrow(n);
    *(uint4*)((bf16_t*)pset + (row << 7) + ((k8 ^ (row & 15)) << 3)) = *(const uint4*)t;
    return;
  }
  if (pblk >= 88) {        // 5 x Wdown [64x128] images
    const int item = (pblk - 88) * 256 + tid;
    const int m = item >> 10, w = item & 1023;
    const int n = w >> 4, k8 = w & 15;
    const float* src = W_down + (m + 1) * 8192;
    bf16_t* img = (bf16_t*)(wdn_img + m * 16384);
    bf16_t t[8];
#pragma unroll
    for (int j = 0; j < 8; ++j) t[j] = (bf16_t)src[(k8 * 8 + j) * 64 + n];
    const int row = permrow(n);
    *(uint4*)(img + (row << 7) + ((k8 ^ (row & 15)) << 3)) = *(const uint4*)t;
    return;
  }
  // 11 x [128x128] images
  const int item = pblk * 256 + tid;
  const int m = item >> 11, w = item & 2047;
  const int n = w >> 4, k8 = w & 15;
  const float* src; char* img;
  if (m == 0)      { src = W_ji;             img = wm_img; }
  else if (m <= 5) { src = W_kj + m * 16384; img = wm_img + m * 32768; }
  else if (m == 6) { src = rb1;   img = pset + 1 * 32768; }
  else if (m == 7) { src = rb2;   img = pset + 2 * 32768; }
  else if (m == 8) { src = W_lin; img = pset + 3 * 32768; }
  else if (m == 9) { src = ra1;   img = pset + 4 * 32768; }
  else             { src = ra2;   img = pset + 5 * 32768; }
  bf16_t t[8];
#pragma unroll
  for (int j = 0; j < 8; ++j) t[j] = (bf16_t)src[(k8 * 8 + j) * 128 + n];
  const int row = permrow(n);
  *(uint4*)((bf16_t*)img + (row << 7) + ((k8 ^ (row & 15)) << 3)) = *(const uint4*)t;
}

// =====================  K1: edge-level GEMMs (bt-bucketed)  =====================
// bid<1024: x_ji (tile-contig, DMA). bid<2048: branch-5 down5 (tile-contig, DMA).
// bid>=2048: bucket blocks (b = (bid-2048)>>10, 64 same-bt edges gathered from
// btlist; x rows re-swizzled from ximg via 16B register copy); write down_bt[e].
// Only branches actually consumed downstream are computed (~53% less work).
__global__ __launch_bounds__(256, 3)
void edge_kernel(const bf16_t* __restrict__ ximg, const float* __restrict__ rbf,
                 const float* __restrict__ b_kj, const float* __restrict__ b_ji,
                 const char* __restrict__ wm_img, const char* __restrict__ wdn_img,
                 const bf16_t* __restrict__ wcb,
                 const int* __restrict__ btlist, const int* __restrict__ bcnt,
                 bf16_t* __restrict__ x_ji_out, bf16_t* __restrict__ down5,
                 bf16_t* __restrict__ down_bt)
{
  __shared__ __align__(16) bf16_t xA[64 * 128];    // 16K; tmp overwrites in place
  __shared__ __align__(16) bf16_t Wb[128 * 128];   // 32K; Wdn reuses first 16K
  __shared__ __align__(16) bf16_t wcbS[128 * 8];   // 2K (this branch's slice)
  __shared__ __align__(16) bf16_t rbfS[64 * 8];    // 1K
  __shared__ float biasS[128];                     // 0.5K  -> total 52,736 B

  const int tid = threadIdx.x;
  const int lane = tid & 63, wv = tid >> 6;
  const int q = lane >> 4, l16 = lane & 15;
  const int mb = (wv >> 1) * 32, nb = (wv & 1) * 64;
  const int bid = blockIdx.x;

  int br, R = 0, bkt = 0, cbase = 0, valid = 0;
  bool bucket = false;
  if (bid < 1024)      { br = 0; R = bid * 64; }
  else if (bid < 2048) { br = 5; R = (bid - 1024) * 64; }
  else {
    bkt = (bid - 2048) >> 10;            // 0..3
    cbase = ((bid - 2048) & 1023) * 64;
    valid = bcnt[bkt];
    if (cbase >= valid) return;          // empty chunk
    br = bkt + 1;
    bucket = true;
  }
  const int* elist = btlist + bkt * E_N;  // valid only when bucket

  // ---- staging ----
  if (!bucket) {
    const char* xs = (const char*)(ximg + (size_t)(R >> 6) * 8192);
    char* xd = (char*)xA;
#pragma unroll
    for (int c = 0; c < 4; ++c) {
      const int off = (c * 4 + wv) * 1024 + lane * 16;
      g2l16(xs + off, xd + off);
    }
  } else {
    // gathered rows, re-swizzled src->dst (both XOR patterns)
    for (int i = tid; i < 1024; i += 256) {
      const int lr = i >> 4, c = i & 15;
      const int gidx = cbase + lr;
      if (gidx < valid) {
        const int e = elist[gidx];
        const uint4 v = *(const uint4*)(ximg + ((size_t)(e >> 6) << 13) +
                                        ((e & 63) << 7) + ((c ^ (e & 15)) << 3));
        *(uint4*)(xA + (lr << 7) + ((c ^ (lr & 15)) << 3)) = v;
      }
    }
  }
  { // weight image DMA
    const char* wsrc = wm_img + (size_t)br * 32768;
    char* wd = (char*)Wb;
#pragma unroll
    for (int c = 0; c < 8; ++c) {
      const int off = (c * 4 + wv) * 1024 + lane * 16;
      g2l16(wsrc + off, wd + off);
    }
  }
  if (br == 0) {
    if (tid < 128) biasS[tid] = b_ji[tid];
  } else {
    if (tid < 128) biasS[tid] = b_kj[br * 128 + tid];
    if (wv < 2) {   // wcb slice 2KB via DMA
      const char* cs = (const char*)(wcb + (size_t)(br - 1) * 1024);
      const int off = wv * 1024 + lane * 16;
      g2l16(cs + off, (char*)wcbS + off);
    }
    if (tid < 64) {
      int e = EINV;
      if (!bucket) e = R + tid;
      else if (cbase + tid < valid) e = elist[cbase + tid];
      if (e != EINV) {
        const float* rg = rbf + (size_t)e * 6;
        bf16_t t[8] = {(bf16_t)rg[0], (bf16_t)rg[1], (bf16_t)rg[2],
                       (bf16_t)rg[3], (bf16_t)rg[4], (bf16_t)rg[5],
                       (bf16_t)0.f, (bf16_t)0.f};
        *(uint4*)(rbfS + tid * 8) = *(const uint4*)t;
      }
    }
  }
  __syncthreads();                              // barrier 1 (drains vmcnt)

  f32x4 acc[2][4] = {};
  gemm_tile<4, 4>(xA, Wb, mb, nb, l16, q, acc);

  if (br == 0) {
#pragma unroll
    for (int ti = 0; ti < 2; ++ti)
#pragma unroll
      for (int r = 0; r < 4; ++r) {
        const int row = mb + ti * 16 + q * 4 + r;
#pragma unroll
        for (int gl = 0; gl < 2; ++gl) {
          const int col0 = nb + gl * 32 + 2 * l16;
          const float2 b2 = *(const float2*)&biasS[col0];
          *(uint32_t*)&x_ji_out[(size_t)(R + row) * 128 + col0] =
              pack_bf16(silu_f(acc[ti][2 * gl][r] + b2.x),
                        silu_f(acc[ti][2 * gl + 1][r] + b2.y));
        }
      }
    return;
  }

  __syncthreads();                              // barrier 2: xA/Wb reads done

  { // Wdn -> Wb[0:16K] via DMA (in flight during tmp phase)
    const char* ds = wdn_img + (size_t)(br - 1) * 16384;
    char* dd = (char*)Wb;
#pragma unroll
    for (int c = 0; c < 4; ++c) {
      const int off = (c * 4 + wv) * 1024 + lane * 16;
      g2l16(ds + off, dd + off);
    }
  }

  // rbf_p dots + tmp = silu(x@Wkj + b) * rbf_p  -> in place into xA
  float wc[2][2][6];
#pragma unroll
  for (int gl = 0; gl < 2; ++gl)
#pragma unroll
    for (int j = 0; j < 2; ++j) {
      const int col = nb + gl * 32 + 2 * l16 + j;
      bf16x8 w8 = *(const bf16x8*)&wcbS[col * 8];
#pragma unroll
      for (int c = 0; c < 6; ++c) wc[gl][j][c] = (float)w8[c];
    }
#pragma unroll
  for (int ti = 0; ti < 2; ++ti)
#pragma unroll
    for (int r = 0; r < 4; ++r) {
      const int row = mb + ti * 16 + q * 4 + r;
      bf16x8 rv8 = *(const bf16x8*)&rbfS[row * 8];
      float rv[6];
#pragma unroll
      for (int c = 0; c < 6; ++c) rv[c] = (float)rv8[c];
#pragma unroll
      for (int gl = 0; gl < 2; ++gl) {
        const int col0 = nb + gl * 32 + 2 * l16;
        const float2 b2 = *(const float2*)&biasS[col0];
        float p0 = 0.f, p1 = 0.f;
#pragma unroll
        for (int c = 0; c < 6; ++c) {
          p0 += rv[c] * wc[gl][0][c];
          p1 += rv[c] * wc[gl][1][c];
        }
        const float v0 = silu_f(acc[ti][2 * gl][r] + b2.x) * p0;
        const float v1 = silu_f(acc[ti][2 * gl + 1][r] + b2.y) * p1;
        *(uint32_t*)&xA[(row << 7) + ((((col0 >> 3) ^ (row & 15)) << 3) | (col0 & 7))] =
            pack_bf16(v0, v1);
      }
    }
  __syncthreads();                              // barrier 3 (drains Wdn DMA)

  const int nb2 = (wv & 1) * 32;
  f32x4 acc2[2][2] = {};
  gemm_tile<4, 2>(xA, Wb, mb, nb2, l16, q, acc2);
  bf16_t* outp = bucket ? down_bt : down5;
#pragma unroll
  for (int ti = 0; ti < 2; ++ti)
#pragma unroll
    for (int r = 0; r < 4; ++r) {
      const int row = mb + ti * 16 + q * 4 + r;
      int e;
      if (!bucket) e = R + row;
      else {
        if (cbase + row >= valid) continue;
        e = elist[cbase + row];
      }
      const int col0 = nb2 + 2 * l16;
      *(uint32_t*)&outp[(size_t)e * 64 + col0] =
          pack_bf16(silu_f(acc2[ti][0][r]), silu_f(acc2[ti][1][r]));
    }
}

// =====================  K2: per-edge gather (standalone, high occupancy)  ==========
// 8 blocks/CU (12KB LDS). k-loop unrolled by 2 with clamped index; down reads
// select base pointer (down5 vs down_bt) per triplet's branch.
__global__ __launch_bounds__(256, 8)
void gather_kernel(const int* __restrict__ cnt, const int* __restrict__ list,
                   const uint32_t* __restrict__ meta, const float* __restrict__ c8g,
                   const float* __restrict__ Wsbf2, const bf16_t* __restrict__ down5,
                   const bf16_t* __restrict__ down_bt,
                   const float* __restrict__ alpha_p, const int* __restrict__ ovf,
                   float* __restrict__ xkj)
{
  __shared__ float sW2[3072];   // [6][8][64]
  for (int i = threadIdx.x; i < 3072; i += 256) sW2[i] = Wsbf2[i];
  __syncthreads();

  const int e = blockIdx.x * 4 + (threadIdx.x >> 6);
  const int j = threadIdx.x & 63;
  const float alpha = alpha_p[0], oma = 1.f - alpha;
  const float* w5 = &sW2[5 * 512 + j];

  int n = cnt[e];
  if (n > CAP) n = CAP;

  // lane-parallel prefetch: lane k (k<16) holds list/meta entry k
  int tk = 0; uint32_t mk = 0;
  if ((j & 15) < n) {
    tk = list[e * CAP + (j & 15)];
    mk = meta[tk];
  }

  float acc = 0.f;
  const int nn = (n + 1) & ~1;
  for (int k0 = 0; k0 < nn; k0 += 2) {
    const int k1 = (k0 + 1 < n) ? k0 + 1 : n - 1;
    const float sc1 = (k0 + 1 < n) ? 1.f : 0.f;
    const int t0 = __builtin_amdgcn_readfirstlane(__shfl(tk, k0, 64));
    const uint32_t m0 = __builtin_amdgcn_readfirstlane(__shfl(mk, k0, 64));
    const int t1 = __builtin_amdgcn_readfirstlane(__shfl(tk, k1, 64));
    const uint32_t m1 = __builtin_amdgcn_readfirstlane(__shfl(mk, k1, 64));
    const int kj0 = m0 & 0xffff, b0 = m0 >> 16;
    const int kj1 = m1 & 0xffff, b1 = m1 >> 16;
    const bf16_t* pb0 = (b0 == 5) ? down5 : down_bt;
    const bf16_t* pb1 = (b1 == 5) ? down5 : down_bt;
    const float g5a = (float)down5[(size_t)kj0 * 64 + j];
    const float gba = (float)pb0[(size_t)kj0 * 64 + j];
    const float g5b = (float)down5[(size_t)kj1 * 64 + j];
    const float gbb = (float)pb1[(size_t)kj1 * 64 + j];
    const float* cp0 = c8g + (size_t)t0 * 16;
    const float* cp1 = c8g + (size_t)t1 * 16;
    float d5a = 0.f, dba = 0.f, d5b = 0.f, dbb = 0.f;
#pragma unroll
    for (int c = 0; c < 8; ++c) {
      d5a += cp0[c]     * w5[c * 64];
      dba += cp0[8 + c] * sW2[b0 * 512 + c * 64 + j];
      d5b += cp1[c]     * w5[c * 64];
      dbb += cp1[8 + c] * sW2[b1 * 512 + c * 64 + j];
    }
    acc += alpha * g5a * d5a + oma * gba * dba;
    acc += sc1 * (alpha * g5b * d5b + oma * gbb * dbb);
  }

  const int oc = ovf[0];       // normally 0; full correctness fallback
  for (int k = 0; k < oc; ++k) {
    const int ji = ovf[2 + 2 * k + 1];
    if (ji != e) continue;
    const int t = ovf[2 + 2 * k];
    const uint32_t m = meta[t];
    const int kj = m & 0xffff;
    const int b  = m >> 16;
    const bf16_t* pb = (b == 5) ? down5 : down_bt;
    const float g5 = (float)down5[(size_t)kj * 64 + j];
    const float gb = (float)pb[(size_t)kj * 64 + j];
    const float* cp = c8g + (size_t)t * 16;
    float d5 = 0.f, db = 0.f;
#pragma unroll
    for (int c = 0; c < 8; ++c) {
      d5 += cp[c]     * w5[c * 64];
      db += cp[8 + c] * sW2[b * 512 + c * 64 + j];
    }
    acc += alpha * g5 * d5 + oma * gb * db;
  }

  xkj[(size_t)e * 64 + j] = acc;
}

// =====================  K3: fused epilogue chain (R7-proven)  =====================
// LDS 50.2 KB -> 3 blocks/CU: single in-place data buffer, bias double-buffered,
// weights via DMA.
__global__ __launch_bounds__(256, 3)
void epi_kernel(const float* __restrict__ x, const bf16_t* __restrict__ x_ji,
                const float* __restrict__ xkj, const char* __restrict__ pset,
                const float* __restrict__ rb1_b, const float* __restrict__ rb2_b,
                const float* __restrict__ lin_b, const float* __restrict__ ra1_b,
                const float* __restrict__ ra2_b,
                float* __restrict__ out)
{
  __shared__ __align__(16) bf16_t buf[64 * 128];   // 16K, in-place A tile
  __shared__ __align__(16) bf16_t Wb[128 * 128];   // 32K
  __shared__ float biasS[2][128];                  // 1K  -> total 50,176 B

  const int tid = threadIdx.x;
  const int lane = tid & 63, wv = tid >> 6;
  const int q = lane >> 4, l16 = lane & 15;
  const int mb = (wv >> 1) * 32, nb = (wv & 1) * 64;
  const int R = blockIdx.x * 64;

#define DMA_W(SLOT) do {                                                         \
    const char* ps_ = pset + (size_t)(SLOT) * 32768;                             \
    char* wd_ = (char*)Wb;                                                       \
    _Pragma("unroll")                                                            \
    for (int c_ = 0; c_ < 8; ++c_) {                                             \
      const int off_ = (c_ * 4 + wv) * 1024 + lane * 16;                         \
      g2l16(ps_ + off_, wd_ + off_);                                             \
    }                                                                            \
  } while (0)

  stage_x<16>(buf, xkj + (size_t)R * 64, tid);
  DMA_W(0);                                     // W_up image
  __syncthreads();

  f32x4 hreg[2][4];
  { // stage 0: h = x_ji + silu(xkj @ W_up)  -> buf (in place)
    f32x4 acc[2][4] = {};
    gemm_tile<2, 4>(buf, Wb, mb, nb, l16, q, acc);
    __syncthreads();                            // all reads of buf/Wb done
#pragma unroll
    for (int ti = 0; ti < 2; ++ti)
#pragma unroll
      for (int r = 0; r < 4; ++r) {
        const int row = mb + ti * 16 + q * 4 + r;
#pragma unroll
        for (int gl = 0; gl < 2; ++gl) {
          const int col0 = nb + gl * 32 + 2 * l16;
          union { uint32_t u; bf16x2 h; } xj;
          xj.u = *(const uint32_t*)&x_ji[(size_t)(R + row) * 128 + col0];
          const float h0 = (float)xj.h[0] + silu_f(acc[ti][2 * gl][r]);
          const float h1 = (float)xj.h[1] + silu_f(acc[ti][2 * gl + 1][r]);
          hreg[ti][2 * gl][r] = h0;
          hreg[ti][2 * gl + 1][r] = h1;
          *(uint32_t*)&buf[(row << 7) + ((((col0 >> 3) ^ (row & 15)) << 3) | (col0 & 7))] =
              pack_bf16(h0, h1);
        }
      }
    DMA_W(1);
    if (tid < 128) biasS[0][tid] = rb1_b[tid];
    __syncthreads();
  }

// stage K (1..5): gemm from buf, barrier, write phase (bias[(K-1)&1], BODY),
// prefetch next W/bias (K<5), barrier.
#define EPI_STAGE(K, NEXTSLOT, NEXTBIAS, BODY)                                   \
  {                                                                              \
    f32x4 acc[2][4] = {};                                                        \
    gemm_tile<4, 4>(buf, Wb, mb, nb, l16, q, acc);                               \
    __syncthreads();                                                             \
    const float* bs_ = biasS[((K) - 1) & 1];                                     \
    _Pragma("unroll")                                                            \
    for (int ti = 0; ti < 2; ++ti)                                               \
      _Pragma("unroll")                                                          \
      for (int r = 0; r < 4; ++r) {                                              \
        const int row = mb + ti * 16 + q * 4 + r;                                \
        _Pragma("unroll")                                                        \
        for (int gl = 0; gl < 2; ++gl) {                                         \
          const int col0 = nb + gl * 32 + 2 * l16;                               \
          const float2 b2 = *(const float2*)&bs_[col0];                          \
          const float g0 = acc[ti][2 * gl][r] + b2.x;                            \
          const float g1 = acc[ti][2 * gl + 1][r] + b2.y;                        \
          BODY                                                                   \
        }                                                                        \
      }                                                                          \
    if ((K) < 5) {                                                               \
      DMA_W(NEXTSLOT);                                                           \
      if (tid < 128) biasS[(K) & 1][tid] = NEXTBIAS[tid];                        \
      __syncthreads();                                                           \
    }                                                                            \
  }

  // stage 1: u = silu(h @ rb1 + b) -> buf
  EPI_STAGE(1, 2, rb2_b, {
    *(uint32_t*)&buf[(row << 7) + ((((col0 >> 3) ^ (row & 15)) << 3) | (col0 & 7))] =
        pack_bf16(silu_f(g0), silu_f(g1));
  })

  // stage 2: h += silu(u @ rb2 + b) -> buf
  EPI_STAGE(2, 3, lin_b, {
    const float h0 = hreg[ti][2 * gl][r] + silu_f(g0);
    const float h1 = hreg[ti][2 * gl + 1][r] + silu_f(g1);
    hreg[ti][2 * gl][r] = h0; hreg[ti][2 * gl + 1][r] = h1;
    *(uint32_t*)&buf[(row << 7) + ((((col0 >> 3) ^ (row & 15)) << 3) | (col0 & 7))] =
        pack_bf16(h0, h1);
  })

  // stage 3: h = silu(h @ W_lin + b) + x -> buf
  EPI_STAGE(3, 4, ra1_b, {
    const float2 xv = *(const float2*)&x[(size_t)(R + row) * 128 + col0];
    const float h0 = silu_f(g0) + xv.x;
    const float h1 = silu_f(g1) + xv.y;
    hreg[ti][2 * gl][r] = h0; hreg[ti][2 * gl + 1][r] = h1;
    *(uint32_t*)&buf[(row << 7) + ((((col0 >> 3) ^ (row & 15)) << 3) | (col0 & 7))] =
        pack_bf16(h0, h1);
  })

  // stage 4: u = silu(h @ ra1 + b) -> buf
  EPI_STAGE(4, 5, ra2_b, {
    *(uint32_t*)&buf[(row << 7) + ((((col0 >> 3) ^ (row & 15)) << 3) | (col0 & 7))] =
        pack_bf16(silu_f(g0), silu_f(g1));
  })

  // stage 5: out = h + silu(u @ ra2 + b)   (global write only)
  EPI_STAGE(5, 0, ra2_b, {
    float2 o;
    o.x = hreg[ti][2 * gl][r] + silu_f(g0);
    o.y = hreg[ti][2 * gl + 1][r] + silu_f(g1);
    *(float2*)&out[(size_t)(R + row) * 128 + col0] = o;
  })
#undef EPI_STAGE
#undef DMA_W
}

extern "C" void kernel_launch(void* const* d_in, const int* in_sizes, int n_in,
                              void* d_out, int out_size, void* d_ws, size_t ws_size,
                              hipStream_t stream)
{
  (void)in_sizes; (void)n_in; (void)out_size; (void)ws_size;
  const float* x      = (const float*)d_in[0];
  const float* rbf    = (const float*)d_in[1];
  const float* sbf    = (const float*)d_in[2];
  const int*   idx_kj = (const int*)d_in[3];
  const int*   idx_ji = (const int*)d_in[4];
  const int*   bt     = (const int*)d_in[5];
  const float* alpha  = (const float*)d_in[7];
  const float* W_kj   = (const float*)d_in[8];
  const float* b_kj   = (const float*)d_in[9];
  const float* W_rbf1 = (const float*)d_in[10];
  const float* W_rbf2 = (const float*)d_in[11];
  const float* W_sbf1 = (const float*)d_in[12];
  const float* W_sbf2 = (const float*)d_in[13];
  const float* W_down = (const float*)d_in[14];
  const float* W_ji   = (const float*)d_in[15];
  const float* b_ji   = (const float*)d_in[16];
  const float* W_up   = (const float*)d_in[17];
  const float* rb1_w  = (const float*)d_in[18];
  const float* rb1_b  = (const float*)d_in[19];
  const float* rb2_w  = (const float*)d_in[20];
  const float* rb2_b  = (const float*)d_in[21];
  const float* W_lin  = (const float*)d_in[22];
  const float* b_lin  = (const float*)d_in[23];
  const float* ra1_w  = (const float*)d_in[24];
  const float* ra1_b  = (const float*)d_in[25];
  const float* ra2_w  = (const float*)d_in[26];
  const float* ra2_b  = (const float*)d_in[27];

  char* ws = (char*)d_ws;
  bf16_t* down5   = (bf16_t*)(ws);                // E*64*2    =  8,388,608
  bf16_t* down_bt = (bf16_t*)(ws + 8388608);      // E*64*2    =  8,388,608
  bf16_t* x_ji    = (bf16_t*)(ws + 16777216);     // E*128*2   = 16,777,216
  bf16_t* ximg    = (bf16_t*)(ws + 33554432);     // E*128*2   = 16,777,216
  float*  xkj     = (float*) (ws + 50331648);     // E*64*4    = 16,777,216
  char*   wm_img  = ws + 67108864;                // 6*32768   =    196,608
  char*   wdn_img = ws + 67305472;                // 5*16384   =     81,920
  char*   pset    = ws + 67387392;                // 6*32768   =    196,608
  bf16_t* wcb     = (bf16_t*)(ws + 67584000);     // 5*128*8*2 =     10,240
  float*    c8g   = (float*)   (ws + 67594240);   // T*16*4    = 16,777,216
  uint32_t* meta  = (uint32_t*)(ws + 84371456);   // T*4       =  1,048,576
  int*      list  = (int*)     (ws + 85420032);   // E*CAP*4   =  4,194,304
  int*      btlist= (int*)     (ws + 89614336);   // 4*E*4     =  1,048,576
  int*      cnt   = (int*)     (ws + 90662912);   // E*4       =    262,144
  int*      bcnt  = (int*)     (ws + 90925056);   // 4*4       =         16
  int*      ovf   = (int*)     (ws + 90925072);   // 8 + 2*T*4 =  2,097,160

  hipMemsetAsync(cnt, 0, 262144 + 16 + 8, stream);  // cnt + bcnt + ovf[0..1]
  // fused prep + c8 + bt-bucket build
  prep_c8_kernel<<<5491, 256, 0, stream>>>(W_ji, W_kj, W_down, W_up, rb1_w,
                                           rb2_w, W_lin, ra1_w, ra2_w, W_rbf1,
                                           W_rbf2, x, wm_img, wdn_img, pset,
                                           wcb, ximg, sbf, idx_kj, idx_ji, bt,
                                           W_sbf1, c8g, meta, cnt, list, ovf,
                                           btlist, bcnt);
  edge_kernel<<<6144, 256, 0, stream>>>(ximg, rbf, b_kj, b_ji, wm_img, wdn_img,
                                        wcb, btlist, bcnt, x_ji, down5, down_bt);
  gather_kernel<<<E_N / 4, 256, 0, stream>>>(cnt, list, meta, c8g, W_sbf2,
                                             down5, down_bt, alpha, ovf, xkj);
  epi_kernel<<<E_N / 64, 256, 0, stream>>>(x, x_ji, xkj, pset,
                                           rb1_b, rb2_b, b_lin, ra1_b, ra2_b,
                                           (float*)d_out);
}

// Round 12
// 365.136 us; speedup vs baseline: 1.6582x; 1.6582x over previous
//
#include <hip/hip_runtime.h>
#include <hip/hip_bf16.h>
#include <stdint.h>

typedef __bf16 bf16_t;
typedef bf16_t bf16x8 __attribute__((ext_vector_type(8)));
typedef bf16_t bf16x2 __attribute__((ext_vector_type(2)));
typedef float f32x4 __attribute__((ext_vector_type(4)));

#define E_N 65536
#define T_N 262144
#define CAP 16          // bucket capacity per edge (avg occupancy 4)
#define OVF_MAX T_N     // overflow list can hold every triplet -> always correct
#define EINV 0x7fffffff

__device__ __forceinline__ float silu_f(float v) {
  return v / (1.0f + __expf(-v));
}

// B-row permutation: LDS row r = tj*16+i holds real output column
// 32*(tj>>1) + 2*i + (tj&1), so each lane's acc[2g],acc[2g+1] are 2
// consecutive real columns -> bf16x2 stores everywhere.
__device__ __forceinline__ int permrow(int n) {
  return (n & ~31) | ((n & 1) << 4) | ((n & 30) >> 1);
}

__device__ __forceinline__ uint32_t pack_bf16(float a, float b) {
  union { bf16x2 h; uint32_t u; } u;
  u.h[0] = (bf16_t)a; u.h[1] = (bf16_t)b;
  return u.u;
}

// ---- async global->LDS DMA (16B per lane; LDS dst = uniform base + lane*16) ----
__device__ __forceinline__ void g2l16(const void* g, void* l) {
  __builtin_amdgcn_global_load_lds(
      (const __attribute__((address_space(1))) void*)g,
      (__attribute__((address_space(3))) void*)l, 16, 0, 0);
}

// ---- MFMA tile GEMM on swizzled stride-128 LDS tiles ----
// element (row,k) stored at row*128 + (((k>>3) ^ (row&15))<<3) + (k&7)
template<int KI, int NTJ>
__device__ __forceinline__ void gemm_tile(const bf16_t* A, const bf16_t* B,
                                          int mb, int nb, int l16, int q,
                                          f32x4 (&acc)[2][NTJ]) {
#pragma unroll
  for (int kt = 0; kt < KI; ++kt) {
    const int sw = ((kt * 4 + q) ^ l16) << 3;
    bf16x8 a0 = *(const bf16x8*)(A + ((mb + l16) << 7) + sw);
    bf16x8 a1 = *(const bf16x8*)(A + ((mb + 16 + l16) << 7) + sw);
#pragma unroll
    for (int tj = 0; tj < NTJ; ++tj) {
      bf16x8 b = *(const bf16x8*)(B + ((nb + tj * 16 + l16) << 7) + sw);
      acc[0][tj] = __builtin_amdgcn_mfma_f32_16x16x32_bf16(a0, b, acc[0][tj], 0, 0, 0);
      acc[1][tj] = __builtin_amdgcn_mfma_f32_16x16x32_bf16(a1, b, acc[1][tj], 0, 0, 0);
    }
  }
}

// Stage fp32 [64][K] tile -> swizzled bf16 LDS. C4 = K/4.
template<int C4>
__device__ __forceinline__ void stage_x(bf16_t* dst, const float* src, int tid) {
  const float4* g = (const float4*)src;
#pragma unroll
  for (int i = tid; i < 64 * C4; i += 256) {
    const int row = i / C4, c4 = i % C4;
    float4 v = g[i];
    bf16_t t[4] = {(bf16_t)v.x, (bf16_t)v.y, (bf16_t)v.z, (bf16_t)v.w};
    *(uint2*)(dst + (row << 7) + ((((c4 >> 1) ^ (row & 15)) << 3) | ((c4 & 1) << 2))) =
        *(const uint2*)t;
  }
}

// =====================  K0: fused preprocessing + triplet c8 + bt-buckets  ========
// blocks 0..4095: c8 projection + CSR bucket build.
// blocks 4096..5234: weight LDS-images, wcb fusion, swizzled x-tile images.
// blocks 5235..5490: bt-bucket build, WAVE-AGGREGATED atomics (R11's divergent
// per-lane atomicAdd onto 4 addresses serialized ~52K RMWs = 328us; ballot +
// one atomicAdd per wave per bucket cuts it to <=4K aggregated atomics).
__global__ __launch_bounds__(256, 4)
void prep_c8_kernel(
    const float* __restrict__ W_ji, const float* __restrict__ W_kj,
    const float* __restrict__ W_down, const float* __restrict__ W_up,
    const float* __restrict__ rb1, const float* __restrict__ rb2,
    const float* __restrict__ W_lin, const float* __restrict__ ra1,
    const float* __restrict__ ra2, const float* __restrict__ W_rbf1,
    const float* __restrict__ W_rbf2, const float* __restrict__ x,
    char* __restrict__ wm_img, char* __restrict__ wdn_img,
    char* __restrict__ pset, bf16_t* __restrict__ wcb,
    bf16_t* __restrict__ ximg,
    const float* __restrict__ sbf, const int* __restrict__ idx_kj,
    const int* __restrict__ idx_ji, const int* __restrict__ bt,
    const float* __restrict__ Wsbf1,
    float* __restrict__ c8g, uint32_t* __restrict__ meta,
    int* __restrict__ cnt, int* __restrict__ list,
    int* __restrict__ ovf, int* __restrict__ btlist, int* __restrict__ bcnt)
{
  __shared__ __align__(16) union {
    bf16_t tile[64 * 128];        // prep x-image path (16 KB)
    struct {                      // c8 path (~23.7 KB)
      float s_sbf[64 * 44];
      float s_W1[2016];           // [6][42][8]
      float s_c8[64 * 16];
      int s_bs[64];
    } c;
  } S;

  const int tid = threadIdx.x;
  const int blk = blockIdx.x;

  if (blk < 4096) {
    // ==================== c8 path ====================
    const int base = blk * 64;

    for (int i = tid; i < 2016; i += 256) S.c.s_W1[i] = Wsbf1[i];
    if (tid < 64) {
      const int t = base + tid;
      const int kj = idx_kj[t];
      const int ji = idx_ji[t];
      const int bs = bt[kj] + 1;   // BT_LIST[b] = b-1 for b>=1; bt in [0,5)
      S.c.s_bs[tid] = bs;
      meta[t] = (uint32_t)kj | ((uint32_t)bs << 16);
      const int pos = atomicAdd(&cnt[ji], 1);
      if (pos < CAP) {
        list[ji * CAP + pos] = t;
      } else {
        const int o = atomicAdd(&ovf[0], 1);
        if (o < OVF_MAX) { ovf[2 + 2 * o] = t; ovf[2 + 2 * o + 1] = ji; }
      }
    }
    {
      const float2* sg = (const float2*)(sbf + (size_t)base * 42);
      for (int i = tid; i < 64 * 21; i += 256) {
        const int r = i / 21, c2 = i - r * 21;
        const float2 v = sg[i];
        S.c.s_sbf[r * 44 + c2 * 2] = v.x;
        S.c.s_sbf[r * 44 + c2 * 2 + 1] = v.y;
      }
    }
    __syncthreads();

    { // c8[i][brr*8+c] : brr=0 -> branch 5, brr=1 -> branch bs
      const int i = tid >> 2;
      const int brr = (tid >> 1) & 1;
      const int cg = tid & 1;
      const int b = brr ? S.c.s_bs[i] : 5;
      const float* w = &S.c.s_W1[b * 336 + cg * 4];
      const float* sb = &S.c.s_sbf[i * 44];
      float a0 = 0.f, a1 = 0.f, a2 = 0.f, a3 = 0.f;
#pragma unroll
      for (int s = 0; s < 42; ++s) {
        const float sv = sb[s];
        const float* ws = w + s * 8;
        a0 += sv * ws[0]; a1 += sv * ws[1]; a2 += sv * ws[2]; a3 += sv * ws[3];
      }
      float* dc = &S.c.s_c8[i * 16 + brr * 8 + cg * 4];
      dc[0] = a0; dc[1] = a1; dc[2] = a2; dc[3] = a3;
    }
    __syncthreads();

    { // coalesced write-out: 256 threads x float4 = 64 triplets x 16 floats
      const float4* s4 = (const float4*)S.c.s_c8;
      float4* g4 = (float4*)(c8g + (size_t)base * 16);
      g4[tid] = s4[tid];
    }
    return;
  }
  if (blk >= 5235) {
    // ==================== bt-bucket build (wave-aggregated) ====================
    const int e = (blk - 5235) * 256 + tid;
    const int bte = bt[e];
    const int lane = tid & 63;
#pragma unroll
    for (int b = 0; b < 4; ++b) {   // bt==4 -> branch 5, covered by down5
      const unsigned long long mask = __ballot(bte == b);
      if (bte == b) {
        const int lt = __popcll(mask & ((1ull << lane) - 1ull));
        const int leader = __ffsll((long long)mask) - 1;
        int base = 0;
        if (lane == leader) base = atomicAdd(&bcnt[b], __popcll(mask));
        base = __shfl(base, leader, 64);
        btlist[b * E_N + base + lt] = e;
      }
    }
    return;
  }

  // ==================== prep path ====================
  const int pblk = blk - 4096;
  if (pblk >= 115) {       // x tile image: stage to LDS then dump linearly
    const int t = pblk - 115;    // 0..1023
    stage_x<32>(S.tile, x + (size_t)t * 8192, tid);
    __syncthreads();
    uint4* dst = (uint4*)(ximg + (size_t)t * 8192);
    const uint4* s = (const uint4*)S.tile;
#pragma unroll
    for (int i = 0; i < 4; ++i) dst[i * 256 + tid] = s[i * 256 + tid];
    return;
  }
  if (pblk >= 112) {       // fused W_rbf1@W_rbf2 -> wcb plain [5][128][8]
    const int o = (pblk - 112) * 256 + tid;
    if (o < 640) {
      const int b = o >> 7, n = o & 127;
      bf16_t t[8];
#pragma unroll
      for (int r = 0; r < 6; ++r) {
        const float* w1 = W_rbf1 + (b + 1) * 48 + r * 8;
        const float* w2 = W_rbf2 + (b + 1) * 1024 + n;
        float s = 0.f;
#pragma unroll
        for (int c = 0; c < 8; ++c) s += w1[c] * w2[c * 128];
        t[r] = (bf16_t)s;
      }
      t[6] = (bf16_t)0.f; t[7] = (bf16_t)0.f;
      *(uint4*)(wcb + (b * 128 + n) * 8) = *(const uint4*)t;
    }
    return;
  }
  if (pblk >= 108) {       // Wup [128 rows, k8<8] image -> pset slot 0
    const int item = (pblk - 108) * 256 + tid;
    const int n = item >> 3, k8 = item & 7;
    bf16_t t[8];
#pragma unroll
    for (int j = 0; j < 8; ++j) t[j] = (bf16_t)W_up[(k8 * 8 + j) * 128 + n];
    const int row = permrow(n);
    *(uint4*)((bf16_t*)pset + (row << 7) + ((k8 ^ (row & 15)) << 3)) = *(const uint4*)t;
    return;
  }
  if (pblk >= 88) {        // 5 x Wdown [64x128] images
    const int item = (pblk - 88) * 256 + tid;
    const int m = item >> 10, w = item & 1023;
    const int n = w >> 4, k8 = w & 15;
    const float* src = W_down + (m + 1) * 8192;
    bf16_t* img = (bf16_t*)(wdn_img + m * 16384);
    bf16_t t[8];
#pragma unroll
    for (int j = 0; j < 8; ++j) t[j] = (bf16_t)src[(k8 * 8 + j) * 64 + n];
    const int row = permrow(n);
    *(uint4*)(img + (row << 7) + ((k8 ^ (row & 15)) << 3)) = *(const uint4*)t;
    return;
  }
  // 11 x [128x128] images
  const int item = pblk * 256 + tid;
  const int m = item >> 11, w = item & 2047;
  const int n = w >> 4, k8 = w & 15;
  const float* src; char* img;
  if (m == 0)      { src = W_ji;             img = wm_img; }
  else if (m <= 5) { src = W_kj + m * 16384; img = wm_img + m * 32768; }
  else if (m == 6) { src = rb1;   img = pset + 1 * 32768; }
  else if (m == 7) { src = rb2;   img = pset + 2 * 32768; }
  else if (m == 8) { src = W_lin; img = pset + 3 * 32768; }
  else if (m == 9) { src = ra1;   img = pset + 4 * 32768; }
  else             { src = ra2;   img = pset + 5 * 32768; }
  bf16_t t[8];
#pragma unroll
  for (int j = 0; j < 8; ++j) t[j] = (bf16_t)src[(k8 * 8 + j) * 128 + n];
  const int row = permrow(n);
  *(uint4*)((bf16_t*)img + (row << 7) + ((k8 ^ (row & 15)) << 3)) = *(const uint4*)t;
}

// =====================  K1: edge-level GEMMs (bt-bucketed)  =====================
// bid<1024: x_ji (tile-contig, DMA). bid<2048: branch-5 down5 (tile-contig, DMA).
// bid>=2048: bucket blocks (b = (bid-2048)>>10, 64 same-bt edges gathered from
// btlist; x rows re-swizzled from ximg via 16B register copy); write down_bt[e].
// Only branches actually consumed downstream are computed (~53% less work).
__global__ __launch_bounds__(256, 3)
void edge_kernel(const bf16_t* __restrict__ ximg, const float* __restrict__ rbf,
                 const float* __restrict__ b_kj, const float* __restrict__ b_ji,
                 const char* __restrict__ wm_img, const char* __restrict__ wdn_img,
                 const bf16_t* __restrict__ wcb,
                 const int* __restrict__ btlist, const int* __restrict__ bcnt,
                 bf16_t* __restrict__ x_ji_out, bf16_t* __restrict__ down5,
                 bf16_t* __restrict__ down_bt)
{
  __shared__ __align__(16) bf16_t xA[64 * 128];    // 16K; tmp overwrites in place
  __shared__ __align__(16) bf16_t Wb[128 * 128];   // 32K; Wdn reuses first 16K
  __shared__ __align__(16) bf16_t wcbS[128 * 8];   // 2K (this branch's slice)
  __shared__ __align__(16) bf16_t rbfS[64 * 8];    // 1K
  __shared__ float biasS[128];                     // 0.5K  -> total 52,736 B

  const int tid = threadIdx.x;
  const int lane = tid & 63, wv = tid >> 6;
  const int q = lane >> 4, l16 = lane & 15;
  const int mb = (wv >> 1) * 32, nb = (wv & 1) * 64;
  const int bid = blockIdx.x;

  int br, R = 0, bkt = 0, cbase = 0, valid = 0;
  bool bucket = false;
  if (bid < 1024)      { br = 0; R = bid * 64; }
  else if (bid < 2048) { br = 5; R = (bid - 1024) * 64; }
  else {
    bkt = (bid - 2048) >> 10;            // 0..3
    cbase = ((bid - 2048) & 1023) * 64;
    valid = bcnt[bkt];
    if (cbase >= valid) return;          // empty chunk
    br = bkt + 1;
    bucket = true;
  }
  const int* elist = btlist + bkt * E_N;  // valid only when bucket

  // ---- staging ----
  if (!bucket) {
    const char* xs = (const char*)(ximg + (size_t)(R >> 6) * 8192);
    char* xd = (char*)xA;
#pragma unroll
    for (int c = 0; c < 4; ++c) {
      const int off = (c * 4 + wv) * 1024 + lane * 16;
      g2l16(xs + off, xd + off);
    }
  } else {
    // gathered rows, re-swizzled src->dst (both XOR patterns)
    for (int i = tid; i < 1024; i += 256) {
      const int lr = i >> 4, c = i & 15;
      const int gidx = cbase + lr;
      if (gidx < valid) {
        const int e = elist[gidx];
        const uint4 v = *(const uint4*)(ximg + ((size_t)(e >> 6) << 13) +
                                        ((e & 63) << 7) + ((c ^ (e & 15)) << 3));
        *(uint4*)(xA + (lr << 7) + ((c ^ (lr & 15)) << 3)) = v;
      }
    }
  }
  { // weight image DMA
    const char* wsrc = wm_img + (size_t)br * 32768;
    char* wd = (char*)Wb;
#pragma unroll
    for (int c = 0; c < 8; ++c) {
      const int off = (c * 4 + wv) * 1024 + lane * 16;
      g2l16(wsrc + off, wd + off);
    }
  }
  if (br == 0) {
    if (tid < 128) biasS[tid] = b_ji[tid];
  } else {
    if (tid < 128) biasS[tid] = b_kj[br * 128 + tid];
    if (wv < 2) {   // wcb slice 2KB via DMA
      const char* cs = (const char*)(wcb + (size_t)(br - 1) * 1024);
      const int off = wv * 1024 + lane * 16;
      g2l16(cs + off, (char*)wcbS + off);
    }
    if (tid < 64) {
      int e = EINV;
      if (!bucket) e = R + tid;
      else if (cbase + tid < valid) e = elist[cbase + tid];
      if (e != EINV) {
        const float* rg = rbf + (size_t)e * 6;
        bf16_t t[8] = {(bf16_t)rg[0], (bf16_t)rg[1], (bf16_t)rg[2],
                       (bf16_t)rg[3], (bf16_t)rg[4], (bf16_t)rg[5],
                       (bf16_t)0.f, (bf16_t)0.f};
        *(uint4*)(rbfS + tid * 8) = *(const uint4*)t;
      }
    }
  }
  __syncthreads();                              // barrier 1 (drains vmcnt)

  f32x4 acc[2][4] = {};
  gemm_tile<4, 4>(xA, Wb, mb, nb, l16, q, acc);

  if (br == 0) {
#pragma unroll
    for (int ti = 0; ti < 2; ++ti)
#pragma unroll
      for (int r = 0; r < 4; ++r) {
        const int row = mb + ti * 16 + q * 4 + r;
#pragma unroll
        for (int gl = 0; gl < 2; ++gl) {
          const int col0 = nb + gl * 32 + 2 * l16;
          const float2 b2 = *(const float2*)&biasS[col0];
          *(uint32_t*)&x_ji_out[(size_t)(R + row) * 128 + col0] =
              pack_bf16(silu_f(acc[ti][2 * gl][r] + b2.x),
                        silu_f(acc[ti][2 * gl + 1][r] + b2.y));
        }
      }
    return;
  }

  __syncthreads();                              // barrier 2: xA/Wb reads done

  { // Wdn -> Wb[0:16K] via DMA (in flight during tmp phase)
    const char* ds = wdn_img + (size_t)(br - 1) * 16384;
    char* dd = (char*)Wb;
#pragma unroll
    for (int c = 0; c < 4; ++c) {
      const int off = (c * 4 + wv) * 1024 + lane * 16;
      g2l16(ds + off, dd + off);
    }
  }

  // rbf_p dots + tmp = silu(x@Wkj + b) * rbf_p  -> in place into xA
  float wc[2][2][6];
#pragma unroll
  for (int gl = 0; gl < 2; ++gl)
#pragma unroll
    for (int j = 0; j < 2; ++j) {
      const int col = nb + gl * 32 + 2 * l16 + j;
      bf16x8 w8 = *(const bf16x8*)&wcbS[col * 8];
#pragma unroll
      for (int c = 0; c < 6; ++c) wc[gl][j][c] = (float)w8[c];
    }
#pragma unroll
  for (int ti = 0; ti < 2; ++ti)
#pragma unroll
    for (int r = 0; r < 4; ++r) {
      const int row = mb + ti * 16 + q * 4 + r;
      bf16x8 rv8 = *(const bf16x8*)&rbfS[row * 8];
      float rv[6];
#pragma unroll
      for (int c = 0; c < 6; ++c) rv[c] = (float)rv8[c];
#pragma unroll
      for (int gl = 0; gl < 2; ++gl) {
        const int col0 = nb + gl * 32 + 2 * l16;
        const float2 b2 = *(const float2*)&biasS[col0];
        float p0 = 0.f, p1 = 0.f;
#pragma unroll
        for (int c = 0; c < 6; ++c) {
          p0 += rv[c] * wc[gl][0][c];
          p1 += rv[c] * wc[gl][1][c];
        }
        const float v0 = silu_f(acc[ti][2 * gl][r] + b2.x) * p0;
        const float v1 = silu_f(acc[ti][2 * gl + 1][r] + b2.y) * p1;
        *(uint32_t*)&xA[(row << 7) + ((((col0 >> 3) ^ (row & 15)) << 3) | (col0 & 7))] =
            pack_bf16(v0, v1);
      }
    }
  __syncthreads();                              // barrier 3 (drains Wdn DMA)

  const int nb2 = (wv & 1) * 32;
  f32x4 acc2[2][2] = {};
  gemm_tile<4, 2>(xA, Wb, mb, nb2, l16, q, acc2);
  bf16_t* outp = bucket ? down_bt : down5;
#pragma unroll
  for (int ti = 0; ti < 2; ++ti)
#pragma unroll
    for (int r = 0; r < 4; ++r) {
      const int row = mb + ti * 16 + q * 4 + r;
      int e;
      if (!bucket) e = R + row;
      else {
        if (cbase + row >= valid) continue;
        e = elist[cbase + row];
      }
      const int col0 = nb2 + 2 * l16;
      *(uint32_t*)&outp[(size_t)e * 64 + col0] =
          pack_bf16(silu_f(acc2[ti][0][r]), silu_f(acc2[ti][1][r]));
    }
}

// =====================  K2: per-edge gather (standalone, high occupancy)  ==========
// 8 blocks/CU (12KB LDS). k-loop unrolled by 2 with clamped index; down reads
// select base pointer (down5 vs down_bt) per triplet's branch.
__global__ __launch_bounds__(256, 8)
void gather_kernel(const int* __restrict__ cnt, const int* __restrict__ list,
                   const uint32_t* __restrict__ meta, const float* __restrict__ c8g,
                   const float* __restrict__ Wsbf2, const bf16_t* __restrict__ down5,
                   const bf16_t* __restrict__ down_bt,
                   const float* __restrict__ alpha_p, const int* __restrict__ ovf,
                   float* __restrict__ xkj)
{
  __shared__ float sW2[3072];   // [6][8][64]
  for (int i = threadIdx.x; i < 3072; i += 256) sW2[i] = Wsbf2[i];
  __syncthreads();

  const int e = blockIdx.x * 4 + (threadIdx.x >> 6);
  const int j = threadIdx.x & 63;
  const float alpha = alpha_p[0], oma = 1.f - alpha;
  const float* w5 = &sW2[5 * 512 + j];

  int n = cnt[e];
  if (n > CAP) n = CAP;

  // lane-parallel prefetch: lane k (k<16) holds list/meta entry k
  int tk = 0; uint32_t mk = 0;
  if ((j & 15) < n) {
    tk = list[e * CAP + (j & 15)];
    mk = meta[tk];
  }

  float acc = 0.f;
  const int nn = (n + 1) & ~1;
  for (int k0 = 0; k0 < nn; k0 += 2) {
    const int k1 = (k0 + 1 < n) ? k0 + 1 : n - 1;
    const float sc1 = (k0 + 1 < n) ? 1.f : 0.f;
    const int t0 = __builtin_amdgcn_readfirstlane(__shfl(tk, k0, 64));
    const uint32_t m0 = __builtin_amdgcn_readfirstlane(__shfl(mk, k0, 64));
    const int t1 = __builtin_amdgcn_readfirstlane(__shfl(tk, k1, 64));
    const uint32_t m1 = __builtin_amdgcn_readfirstlane(__shfl(mk, k1, 64));
    const int kj0 = m0 & 0xffff, b0 = m0 >> 16;
    const int kj1 = m1 & 0xffff, b1 = m1 >> 16;
    const bf16_t* pb0 = (b0 == 5) ? down5 : down_bt;
    const bf16_t* pb1 = (b1 == 5) ? down5 : down_bt;
    const float g5a = (float)down5[(size_t)kj0 * 64 + j];
    const float gba = (float)pb0[(size_t)kj0 * 64 + j];
    const float g5b = (float)down5[(size_t)kj1 * 64 + j];
    const float gbb = (float)pb1[(size_t)kj1 * 64 + j];
    const float* cp0 = c8g + (size_t)t0 * 16;
    const float* cp1 = c8g + (size_t)t1 * 16;
    float d5a = 0.f, dba = 0.f, d5b = 0.f, dbb = 0.f;
#pragma unroll
    for (int c = 0; c < 8; ++c) {
      d5a += cp0[c]     * w5[c * 64];
      dba += cp0[8 + c] * sW2[b0 * 512 + c * 64 + j];
      d5b += cp1[c]     * w5[c * 64];
      dbb += cp1[8 + c] * sW2[b1 * 512 + c * 64 + j];
    }
    acc += alpha * g5a * d5a + oma * gba * dba;
    acc += sc1 * (alpha * g5b * d5b + oma * gbb * dbb);
  }

  const int oc = ovf[0];       // normally 0; full correctness fallback
  for (int k = 0; k < oc; ++k) {
    const int ji = ovf[2 + 2 * k + 1];
    if (ji != e) continue;
    const int t = ovf[2 + 2 * k];
    const uint32_t m = meta[t];
    const int kj = m & 0xffff;
    const int b  = m >> 16;
    const bf16_t* pb = (b == 5) ? down5 : down_bt;
    const float g5 = (float)down5[(size_t)kj * 64 + j];
    const float gb = (float)pb[(size_t)kj * 64 + j];
    const float* cp = c8g + (size_t)t * 16;
    float d5 = 0.f, db = 0.f;
#pragma unroll
    for (int c = 0; c < 8; ++c) {
      d5 += cp[c]     * w5[c * 64];
      db += cp[8 + c] * sW2[b * 512 + c * 64 + j];
    }
    acc += alpha * g5 * d5 + oma * gb * db;
  }

  xkj[(size_t)e * 64 + j] = acc;
}

// =====================  K3: fused epilogue chain (R7-proven)  =====================
// LDS 50.2 KB -> 3 blocks/CU: single in-place data buffer, bias double-buffered,
// weights via DMA.
__global__ __launch_bounds__(256, 3)
void epi_kernel(const float* __restrict__ x, const bf16_t* __restrict__ x_ji,
                const float* __restrict__ xkj, const char* __restrict__ pset,
                const float* __restrict__ rb1_b, const float* __restrict__ rb2_b,
                const float* __restrict__ lin_b, const float* __restrict__ ra1_b,
                const float* __restrict__ ra2_b,
                float* __restrict__ out)
{
  __shared__ __align__(16) bf16_t buf[64 * 128];   // 16K, in-place A tile
  __shared__ __align__(16) bf16_t Wb[128 * 128];   // 32K
  __shared__ float biasS[2][128];                  // 1K  -> total 50,176 B

  const int tid = threadIdx.x;
  const int lane = tid & 63, wv = tid >> 6;
  const int q = lane >> 4, l16 = lane & 15;
  const int mb = (wv >> 1) * 32, nb = (wv & 1) * 64;
  const int R = blockIdx.x * 64;

#define DMA_W(SLOT) do {                                                         \
    const char* ps_ = pset + (size_t)(SLOT) * 32768;                             \
    char* wd_ = (char*)Wb;                                                       \
    _Pragma("unroll")                                                            \
    for (int c_ = 0; c_ < 8; ++c_) {                                             \
      const int off_ = (c_ * 4 + wv) * 1024 + lane * 16;                         \
      g2l16(ps_ + off_, wd_ + off_);                                             \
    }                                                                            \
  } while (0)

  stage_x<16>(buf, xkj + (size_t)R * 64, tid);
  DMA_W(0);                                     // W_up image
  __syncthreads();

  f32x4 hreg[2][4];
  { // stage 0: h = x_ji + silu(xkj @ W_up)  -> buf (in place)
    f32x4 acc[2][4] = {};
    gemm_tile<2, 4>(buf, Wb, mb, nb, l16, q, acc);
    __syncthreads();                            // all reads of buf/Wb done
#pragma unroll
    for (int ti = 0; ti < 2; ++ti)
#pragma unroll
      for (int r = 0; r < 4; ++r) {
        const int row = mb + ti * 16 + q * 4 + r;
#pragma unroll
        for (int gl = 0; gl < 2; ++gl) {
          const int col0 = nb + gl * 32 + 2 * l16;
          union { uint32_t u; bf16x2 h; } xj;
          xj.u = *(const uint32_t*)&x_ji[(size_t)(R + row) * 128 + col0];
          const float h0 = (float)xj.h[0] + silu_f(acc[ti][2 * gl][r]);
          const float h1 = (float)xj.h[1] + silu_f(acc[ti][2 * gl + 1][r]);
          hreg[ti][2 * gl][r] = h0;
          hreg[ti][2 * gl + 1][r] = h1;
          *(uint32_t*)&buf[(row << 7) + ((((col0 >> 3) ^ (row & 15)) << 3) | (col0 & 7))] =
              pack_bf16(h0, h1);
        }
      }
    DMA_W(1);
    if (tid < 128) biasS[0][tid] = rb1_b[tid];
    __syncthreads();
  }

// stage K (1..5): gemm from buf, barrier, write phase (bias[(K-1)&1], BODY),
// prefetch next W/bias (K<5), barrier.
#define EPI_STAGE(K, NEXTSLOT, NEXTBIAS, BODY)                                   \
  {                                                                              \
    f32x4 acc[2][4] = {};                                                        \
    gemm_tile<4, 4>(buf, Wb, mb, nb, l16, q, acc);                               \
    __syncthreads();                                                             \
    const float* bs_ = biasS[((K) - 1) & 1];                                     \
    _Pragma("unroll")                                                            \
    for (int ti = 0; ti < 2; ++ti)                                               \
      _Pragma("unroll")                                                          \
      for (int r = 0; r < 4; ++r) {                                              \
        const int row = mb + ti * 16 + q * 4 + r;                                \
        _Pragma("unroll")                                                        \
        for (int gl = 0; gl < 2; ++gl) {                                         \
          const int col0 = nb + gl * 32 + 2 * l16;                               \
          const float2 b2 = *(const float2*)&bs_[col0];                          \
          const float g0 = acc[ti][2 * gl][r] + b2.x;                            \
          const float g1 = acc[ti][2 * gl + 1][r] + b2.y;                        \
          BODY                                                                   \
        }                                                                        \
      }                                                                          \
    if ((K) < 5) {                                                               \
      DMA_W(NEXTSLOT);                                                           \
      if (tid < 128) biasS[(K) & 1][tid] = NEXTBIAS[tid];                        \
      __syncthreads();                                                           \
    }                                                                            \
  }

  // stage 1: u = silu(h @ rb1 + b) -> buf
  EPI_STAGE(1, 2, rb2_b, {
    *(uint32_t*)&buf[(row << 7) + ((((col0 >> 3) ^ (row & 15)) << 3) | (col0 & 7))] =
        pack_bf16(silu_f(g0), silu_f(g1));
  })

  // stage 2: h += silu(u @ rb2 + b) -> buf
  EPI_STAGE(2, 3, lin_b, {
    const float h0 = hreg[ti][2 * gl][r] + silu_f(g0);
    const float h1 = hreg[ti][2 * gl + 1][r] + silu_f(g1);
    hreg[ti][2 * gl][r] = h0; hreg[ti][2 * gl + 1][r] = h1;
    *(uint32_t*)&buf[(row << 7) + ((((col0 >> 3) ^ (row & 15)) << 3) | (col0 & 7))] =
        pack_bf16(h0, h1);
  })

  // stage 3: h = silu(h @ W_lin + b) + x -> buf
  EPI_STAGE(3, 4, ra1_b, {
    const float2 xv = *(const float2*)&x[(size_t)(R + row) * 128 + col0];
    const float h0 = silu_f(g0) + xv.x;
    const float h1 = silu_f(g1) + xv.y;
    hreg[ti][2 * gl][r] = h0; hreg[ti][2 * gl + 1][r] = h1;
    *(uint32_t*)&buf[(row << 7) + ((((col0 >> 3) ^ (row & 15)) << 3) | (col0 & 7))] =
        pack_bf16(h0, h1);
  })

  // stage 4: u = silu(h @ ra1 + b) -> buf
  EPI_STAGE(4, 5, ra2_b, {
    *(uint32_t*)&buf[(row << 7) + ((((col0 >> 3) ^ (row & 15)) << 3) | (col0 & 7))] =
        pack_bf16(silu_f(g0), silu_f(g1));
  })

  // stage 5: out = h + silu(u @ ra2 + b)   (global write only)
  EPI_STAGE(5, 0, ra2_b, {
    float2 o;
    o.x = hreg[ti][2 * gl][r] + silu_f(g0);
    o.y = hreg[ti][2 * gl + 1][r] + silu_f(g1);
    *(float2*)&out[(size_t)(R + row) * 128 + col0] = o;
  })
#undef EPI_STAGE
#undef DMA_W
}

extern "C" void kernel_launch(void* const* d_in, const int* in_sizes, int n_in,
                              void* d_out, int out_size, void* d_ws, size_t ws_size,
                              hipStream_t stream)
{
  (void)in_sizes; (void)n_in; (void)out_size; (void)ws_size;
  const float* x      = (const float*)d_in[0];
  const float* rbf    = (const float*)d_in[1];
  const float* sbf    = (const float*)d_in[2];
  const int*   idx_kj = (const int*)d_in[3];
  const int*   idx_ji = (const int*)d_in[4];
  const int*   bt     = (const int*)d_in[5];
  const float* alpha  = (const float*)d_in[7];
  const float* W_kj   = (const float*)d_in[8];
  const float* b_kj   = (const float*)d_in[9];
  const float* W_rbf1 = (const float*)d_in[10];
  const float* W_rbf2 = (const float*)d_in[11];
  const float* W_sbf1 = (const float*)d_in[12];
  const float* W_sbf2 = (const float*)d_in[13];
  const float* W_down = (const float*)d_in[14];
  const float* W_ji   = (const float*)d_in[15];
  const float* b_ji   = (const float*)d_in[16];
  const float* W_up   = (const float*)d_in[17];
  const float* rb1_w  = (const float*)d_in[18];
  const float* rb1_b  = (const float*)d_in[19];
  const float* rb2_w  = (const float*)d_in[20];
  const float* rb2_b  = (const float*)d_in[21];
  const float* W_lin  = (const float*)d_in[22];
  const float* b_lin  = (const float*)d_in[23];
  const float* ra1_w  = (const float*)d_in[24];
  const float* ra1_b  = (const float*)d_in[25];
  const float* ra2_w  = (const float*)d_in[26];
  const float* ra2_b  = (const float*)d_in[27];

  char* ws = (char*)d_ws;
  bf16_t* down5   = (bf16_t*)(ws);                // E*64*2    =  8,388,608
  bf16_t* down_bt = (bf16_t*)(ws + 8388608);      // E*64*2    =  8,388,608
  bf16_t* x_ji    = (bf16_t*)(ws + 16777216);     // E*128*2   = 16,777,216
  bf16_t* ximg    = (bf16_t*)(ws + 33554432);     // E*128*2   = 16,777,216
  float*  xkj     = (float*) (ws + 50331648);     // E*64*4    = 16,777,216
  char*   wm_img  = ws + 67108864;                // 6*32768   =    196,608
  char*   wdn_img = ws + 67305472;                // 5*16384   =     81,920
  char*   pset    = ws + 67387392;                // 6*32768   =    196,608
  bf16_t* wcb     = (bf16_t*)(ws + 67584000);     // 5*128*8*2 =     10,240
  float*    c8g   = (float*)   (ws + 67594240);   // T*16*4    = 16,777,216
  uint32_t* meta  = (uint32_t*)(ws + 84371456);   // T*4       =  1,048,576
  int*      list  = (int*)     (ws + 85420032);   // E*CAP*4   =  4,194,304
  int*      btlist= (int*)     (ws + 89614336);   // 4*E*4     =  1,048,576
  int*      cnt   = (int*)     (ws + 90662912);   // E*4       =    262,144
  int*      bcnt  = (int*)     (ws + 90925056);   // 4*4       =         16
  int*      ovf   = (int*)     (ws + 90925072);   // 8 + 2*T*4 =  2,097,160

  hipMemsetAsync(cnt, 0, 262144 + 16 + 8, stream);  // cnt + bcnt + ovf[0..1]
  // fused prep + c8 + bt-bucket build
  prep_c8_kernel<<<5491, 256, 0, stream>>>(W_ji, W_kj, W_down, W_up, rb1_w,
                                           rb2_w, W_lin, ra1_w, ra2_w, W_rbf1,
                                           W_rbf2, x, wm_img, wdn_img, pset,
                                           wcb, ximg, sbf, idx_kj, idx_ji, bt,
                                           W_sbf1, c8g, meta, cnt, list, ovf,
                                           btlist, bcnt);
  edge_kernel<<<6144, 256, 0, stream>>>(ximg, rbf, b_kj, b_ji, wm_img, wdn_img,
                                        wcb, btlist, bcnt, x_ji, down5, down_bt);
  gather_kernel<<<E_N / 4, 256, 0, stream>>>(cnt, list, meta, c8g, W_sbf2,
                                             down5, down_bt, alpha, ovf, xkj);
  epi_kernel<<<E_N / 64, 256, 0, stream>>>(x, x_ji, xkj, pset,
                                           rb1_b, rb2_b, b_lin, ra1_b, ra2_b,
                                           (float*)d_out);
}

// Round 13
// 325.055 us; speedup vs baseline: 1.8627x; 1.1233x over previous
//
#include <hip/hip_runtime.h>
#include <hip/hip_bf16.h>
#include <stdint.h>

typedef __bf16 bf16_t;
typedef bf16_t bf16x8 __attribute__((ext_vector_type(8)));
typedef bf16_t bf16x2 __attribute__((ext_vector_type(2)));
typedef float f32x4 __attribute__((ext_vector_type(4)));

#define E_N 65536
#define T_N 262144
#define CAP 16          // bucket capacity per edge (avg occupancy 4)
#define OVF_MAX T_N     // overflow list can hold every triplet -> always correct
#define EINV 0x7fffffff
#define BCNT_STRIDE 32  // ints; 128B padding so bucket counters don't share a line

__device__ __forceinline__ float silu_f(float v) {
  return v / (1.0f + __expf(-v));
}

// B-row permutation: LDS row r = tj*16+i holds real output column
// 32*(tj>>1) + 2*i + (tj&1), so each lane's acc[2g],acc[2g+1] are 2
// consecutive real columns -> bf16x2 stores everywhere.
__device__ __forceinline__ int permrow(int n) {
  return (n & ~31) | ((n & 1) << 4) | ((n & 30) >> 1);
}

__device__ __forceinline__ uint32_t pack_bf16(float a, float b) {
  union { bf16x2 h; uint32_t u; } u;
  u.h[0] = (bf16_t)a; u.h[1] = (bf16_t)b;
  return u.u;
}

// ---- async global->LDS DMA (16B per lane; LDS dst = uniform base + lane*16) ----
__device__ __forceinline__ void g2l16(const void* g, void* l) {
  __builtin_amdgcn_global_load_lds(
      (const __attribute__((address_space(1))) void*)g,
      (__attribute__((address_space(3))) void*)l, 16, 0, 0);
}

// ---- MFMA tile GEMM on swizzled stride-128 LDS tiles ----
// element (row,k) stored at row*128 + (((k>>3) ^ (row&15))<<3) + (k&7)
template<int KI, int NTJ>
__device__ __forceinline__ void gemm_tile(const bf16_t* A, const bf16_t* B,
                                          int mb, int nb, int l16, int q,
                                          f32x4 (&acc)[2][NTJ]) {
#pragma unroll
  for (int kt = 0; kt < KI; ++kt) {
    const int sw = ((kt * 4 + q) ^ l16) << 3;
    bf16x8 a0 = *(const bf16x8*)(A + ((mb + l16) << 7) + sw);
    bf16x8 a1 = *(const bf16x8*)(A + ((mb + 16 + l16) << 7) + sw);
#pragma unroll
    for (int tj = 0; tj < NTJ; ++tj) {
      bf16x8 b = *(const bf16x8*)(B + ((nb + tj * 16 + l16) << 7) + sw);
      acc[0][tj] = __builtin_amdgcn_mfma_f32_16x16x32_bf16(a0, b, acc[0][tj], 0, 0, 0);
      acc[1][tj] = __builtin_amdgcn_mfma_f32_16x16x32_bf16(a1, b, acc[1][tj], 0, 0, 0);
    }
  }
}

// Stage fp32 [64][K] tile -> swizzled bf16 LDS. C4 = K/4.
template<int C4>
__device__ __forceinline__ void stage_x(bf16_t* dst, const float* src, int tid) {
  const float4* g = (const float4*)src;
#pragma unroll
  for (int i = tid; i < 64 * C4; i += 256) {
    const int row = i / C4, c4 = i % C4;
    float4 v = g[i];
    bf16_t t[4] = {(bf16_t)v.x, (bf16_t)v.y, (bf16_t)v.z, (bf16_t)v.w};
    *(uint2*)(dst + (row << 7) + ((((c4 >> 1) ^ (row & 15)) << 3) | ((c4 & 1) << 2))) =
        *(const uint2*)t;
  }
}

// =====================  K0: fused preprocessing + triplet c8 + bt-buckets  ========
// blocks 0..255:     bt-bucket build (grid FRONT so latency hides under c8/prep;
//                    block-aggregated: 1 atomic per bucket per block, padded lines).
// blocks 256..4351:  c8 projection + CSR bucket build.
// blocks 4352..5490: weight LDS-images, wcb fusion, swizzled x-tile images.
__global__ __launch_bounds__(256, 4)
void prep_c8_kernel(
    const float* __restrict__ W_ji, const float* __restrict__ W_kj,
    const float* __restrict__ W_down, const float* __restrict__ W_up,
    const float* __restrict__ rb1, const float* __restrict__ rb2,
    const float* __restrict__ W_lin, const float* __restrict__ ra1,
    const float* __restrict__ ra2, const float* __restrict__ W_rbf1,
    const float* __restrict__ W_rbf2, const float* __restrict__ x,
    char* __restrict__ wm_img, char* __restrict__ wdn_img,
    char* __restrict__ pset, bf16_t* __restrict__ wcb,
    bf16_t* __restrict__ ximg,
    const float* __restrict__ sbf, const int* __restrict__ idx_kj,
    const int* __restrict__ idx_ji, const int* __restrict__ bt,
    const float* __restrict__ Wsbf1,
    float* __restrict__ c8g, uint32_t* __restrict__ meta,
    int* __restrict__ cnt, int* __restrict__ list,
    int* __restrict__ ovf, int* __restrict__ btlist, int* __restrict__ bcnt)
{
  __shared__ __align__(16) union {
    bf16_t tile[64 * 128];        // prep x-image path (16 KB)
    struct {                      // c8 path (~23.7 KB)
      float s_sbf[64 * 44];
      float s_W1[2016];           // [6][42][8]
      float s_c8[64 * 16];
      int s_bs[64];
    } c;
    struct {                      // bucket path
      int wcnt[4][4];             // [bucket][wave]
      int wbase[4][4];
    } b;
  } S;

  const int tid = threadIdx.x;
  const int blk = blockIdx.x;

  if (blk < 256) {
    // ==================== bt-bucket build (block-aggregated) ====================
    const int e = blk * 256 + tid;
    const int bte = bt[e];
    const int lane = tid & 63, wv = tid >> 6;
    unsigned long long mask[4];
#pragma unroll
    for (int b = 0; b < 4; ++b) {   // bt==4 -> branch 5, covered by down5
      mask[b] = __ballot(bte == b);
      if (lane == 0) S.b.wcnt[b][wv] = __popcll(mask[b]);
    }
    __syncthreads();
    if (tid < 4) {   // thread b: block total -> one global atomic -> wave bases
      const int c0 = S.b.wcnt[tid][0], c1 = S.b.wcnt[tid][1];
      const int c2 = S.b.wcnt[tid][2], c3 = S.b.wcnt[tid][3];
      int base = atomicAdd(&bcnt[tid * BCNT_STRIDE], c0 + c1 + c2 + c3);
      S.b.wbase[tid][0] = base;           base += c0;
      S.b.wbase[tid][1] = base;           base += c1;
      S.b.wbase[tid][2] = base;           base += c2;
      S.b.wbase[tid][3] = base;
    }
    __syncthreads();
    if (bte < 4) {
      const int lt = __popcll(mask[bte] & ((1ull << lane) - 1ull));
      btlist[bte * E_N + S.b.wbase[bte][wv] + lt] = e;
    }
    return;
  }

  if (blk < 4352) {
    // ==================== c8 path ====================
    const int base = (blk - 256) * 64;

    for (int i = tid; i < 2016; i += 256) S.c.s_W1[i] = Wsbf1[i];
    if (tid < 64) {
      const int t = base + tid;
      const int kj = idx_kj[t];
      const int ji = idx_ji[t];
      const int bs = bt[kj] + 1;   // BT_LIST[b] = b-1 for b>=1; bt in [0,5)
      S.c.s_bs[tid] = bs;
      meta[t] = (uint32_t)kj | ((uint32_t)bs << 16);
      const int pos = atomicAdd(&cnt[ji], 1);
      if (pos < CAP) {
        list[ji * CAP + pos] = t;
      } else {
        const int o = atomicAdd(&ovf[0], 1);
        if (o < OVF_MAX) { ovf[2 + 2 * o] = t; ovf[2 + 2 * o + 1] = ji; }
      }
    }
    {
      const float2* sg = (const float2*)(sbf + (size_t)base * 42);
      for (int i = tid; i < 64 * 21; i += 256) {
        const int r = i / 21, c2 = i - r * 21;
        const float2 v = sg[i];
        S.c.s_sbf[r * 44 + c2 * 2] = v.x;
        S.c.s_sbf[r * 44 + c2 * 2 + 1] = v.y;
      }
    }
    __syncthreads();

    { // c8[i][brr*8+c] : brr=0 -> branch 5, brr=1 -> branch bs
      const int i = tid >> 2;
      const int brr = (tid >> 1) & 1;
      const int cg = tid & 1;
      const int b = brr ? S.c.s_bs[i] : 5;
      const float* w = &S.c.s_W1[b * 336 + cg * 4];
      const float* sb = &S.c.s_sbf[i * 44];
      float a0 = 0.f, a1 = 0.f, a2 = 0.f, a3 = 0.f;
#pragma unroll
      for (int s = 0; s < 42; ++s) {
        const float sv = sb[s];
        const float* ws = w + s * 8;
        a0 += sv * ws[0]; a1 += sv * ws[1]; a2 += sv * ws[2]; a3 += sv * ws[3];
      }
      float* dc = &S.c.s_c8[i * 16 + brr * 8 + cg * 4];
      dc[0] = a0; dc[1] = a1; dc[2] = a2; dc[3] = a3;
    }
    __syncthreads();

    { // coalesced write-out: 256 threads x float4 = 64 triplets x 16 floats
      const float4* s4 = (const float4*)S.c.s_c8;
      float4* g4 = (float4*)(c8g + (size_t)base * 16);
      g4[tid] = s4[tid];
    }
    return;
  }

  // ==================== prep path ====================
  const int pblk = blk - 4352;
  if (pblk >= 115) {       // x tile image: stage to LDS then dump linearly
    const int t = pblk - 115;    // 0..1023
    stage_x<32>(S.tile, x + (size_t)t * 8192, tid);
    __syncthreads();
    uint4* dst = (uint4*)(ximg + (size_t)t * 8192);
    const uint4* s = (const uint4*)S.tile;
#pragma unroll
    for (int i = 0; i < 4; ++i) dst[i * 256 + tid] = s[i * 256 + tid];
    return;
  }
  if (pblk >= 112) {       // fused W_rbf1@W_rbf2 -> wcb plain [5][128][8]
    const int o = (pblk - 112) * 256 + tid;
    if (o < 640) {
      const int b = o >> 7, n = o & 127;
      bf16_t t[8];
#pragma unroll
      for (int r = 0; r < 6; ++r) {
        const float* w1 = W_rbf1 + (b + 1) * 48 + r * 8;
        const float* w2 = W_rbf2 + (b + 1) * 1024 + n;
        float s = 0.f;
#pragma unroll
        for (int c = 0; c < 8; ++c) s += w1[c] * w2[c * 128];
        t[r] = (bf16_t)s;
      }
      t[6] = (bf16_t)0.f; t[7] = (bf16_t)0.f;
      *(uint4*)(wcb + (b * 128 + n) * 8) = *(const uint4*)t;
    }
    return;
  }
  if (pblk >= 108) {       // Wup [128 rows, k8<8] image -> pset slot 0
    const int item = (pblk - 108) * 256 + tid;
    const int n = item >> 3, k8 = item & 7;
    bf16_t t[8];
#pragma unroll
    for (int j = 0; j < 8; ++j) t[j] = (bf16_t)W_up[(k8 * 8 + j) * 128 + n];
    const int row = permrow(n);
    *(uint4*)((bf16_t*)pset + (row << 7) + ((k8 ^ (row & 15)) << 3)) = *(const uint4*)t;
    return;
  }
  if (pblk >= 88) {        // 5 x Wdown [64x128] images
    const int item = (pblk - 88) * 256 + tid;
    const int m = item >> 10, w = item & 1023;
    const int n = w >> 4, k8 = w & 15;
    const float* src = W_down + (m + 1) * 8192;
    bf16_t* img = (bf16_t*)(wdn_img + m * 16384);
    bf16_t t[8];
#pragma unroll
    for (int j = 0; j < 8; ++j) t[j] = (bf16_t)src[(k8 * 8 + j) * 64 + n];
    const int row = permrow(n);
    *(uint4*)(img + (row << 7) + ((k8 ^ (row & 15)) << 3)) = *(const uint4*)t;
    return;
  }
  // 11 x [128x128] images
  const int item = pblk * 256 + tid;
  const int m = item >> 11, w = item & 2047;
  const int n = w >> 4, k8 = w & 15;
  const float* src; char* img;
  if (m == 0)      { src = W_ji;             img = wm_img; }
  else if (m <= 5) { src = W_kj + m * 16384; img = wm_img + m * 32768; }
  else if (m == 6) { src = rb1;   img = pset + 1 * 32768; }
  else if (m == 7) { src = rb2;   img = pset + 2 * 32768; }
  else if (m == 8) { src = W_lin; img = pset + 3 * 32768; }
  else if (m == 9) { src = ra1;   img = pset + 4 * 32768; }
  else             { src = ra2;   img = pset + 5 * 32768; }
  bf16_t t[8];
#pragma unroll
  for (int j = 0; j < 8; ++j) t[j] = (bf16_t)src[(k8 * 8 + j) * 128 + n];
  const int row = permrow(n);
  *(uint4*)((bf16_t*)img + (row << 7) + ((k8 ^ (row & 15)) << 3)) = *(const uint4*)t;
}

// =====================  K1: edge-level GEMMs (bt-bucketed)  =====================
// bid<1024: x_ji (tile-contig, DMA). bid<2048: branch-5 down5 (tile-contig, DMA).
// bid>=2048: bucket blocks (b = (bid-2048)>>10, 64 same-bt edges gathered from
// btlist; x rows re-swizzled from ximg via 16B register copy); write down_bt[e].
// Only branches actually consumed downstream are computed (~53% less work).
__global__ __launch_bounds__(256, 3)
void edge_kernel(const bf16_t* __restrict__ ximg, const float* __restrict__ rbf,
                 const float* __restrict__ b_kj, const float* __restrict__ b_ji,
                 const char* __restrict__ wm_img, const char* __restrict__ wdn_img,
                 const bf16_t* __restrict__ wcb,
                 const int* __restrict__ btlist, const int* __restrict__ bcnt,
                 bf16_t* __restrict__ x_ji_out, bf16_t* __restrict__ down5,
                 bf16_t* __restrict__ down_bt)
{
  __shared__ __align__(16) bf16_t xA[64 * 128];    // 16K; tmp overwrites in place
  __shared__ __align__(16) bf16_t Wb[128 * 128];   // 32K; Wdn reuses first 16K
  __shared__ __align__(16) bf16_t wcbS[128 * 8];   // 2K (this branch's slice)
  __shared__ __align__(16) bf16_t rbfS[64 * 8];    // 1K
  __shared__ float biasS[128];                     // 0.5K  -> total 52,736 B

  const int tid = threadIdx.x;
  const int lane = tid & 63, wv = tid >> 6;
  const int q = lane >> 4, l16 = lane & 15;
  const int mb = (wv >> 1) * 32, nb = (wv & 1) * 64;
  const int bid = blockIdx.x;

  int br, R = 0, bkt = 0, cbase = 0, valid = 0;
  bool bucket = false;
  if (bid < 1024)      { br = 0; R = bid * 64; }
  else if (bid < 2048) { br = 5; R = (bid - 1024) * 64; }
  else {
    bkt = (bid - 2048) >> 10;            // 0..3
    cbase = ((bid - 2048) & 1023) * 64;
    valid = bcnt[bkt * BCNT_STRIDE];
    if (cbase >= valid) return;          // empty chunk
    br = bkt + 1;
    bucket = true;
  }
  const int* elist = btlist + bkt * E_N;  // valid only when bucket

  // ---- staging ----
  if (!bucket) {
    const char* xs = (const char*)(ximg + (size_t)(R >> 6) * 8192);
    char* xd = (char*)xA;
#pragma unroll
    for (int c = 0; c < 4; ++c) {
      const int off = (c * 4 + wv) * 1024 + lane * 16;
      g2l16(xs + off, xd + off);
    }
  } else {
    // gathered rows, re-swizzled src->dst (both XOR patterns)
    for (int i = tid; i < 1024; i += 256) {
      const int lr = i >> 4, c = i & 15;
      const int gidx = cbase + lr;
      if (gidx < valid) {
        const int e = elist[gidx];
        const uint4 v = *(const uint4*)(ximg + ((size_t)(e >> 6) << 13) +
                                        ((e & 63) << 7) + ((c ^ (e & 15)) << 3));
        *(uint4*)(xA + (lr << 7) + ((c ^ (lr & 15)) << 3)) = v;
      }
    }
  }
  { // weight image DMA
    const char* wsrc = wm_img + (size_t)br * 32768;
    char* wd = (char*)Wb;
#pragma unroll
    for (int c = 0; c < 8; ++c) {
      const int off = (c * 4 + wv) * 1024 + lane * 16;
      g2l16(wsrc + off, wd + off);
    }
  }
  if (br == 0) {
    if (tid < 128) biasS[tid] = b_ji[tid];
  } else {
    if (tid < 128) biasS[tid] = b_kj[br * 128 + tid];
    if (wv < 2) {   // wcb slice 2KB via DMA
      const char* cs = (const char*)(wcb + (size_t)(br - 1) * 1024);
      const int off = wv * 1024 + lane * 16;
      g2l16(cs + off, (char*)wcbS + off);
    }
    if (tid < 64) {
      int e = EINV;
      if (!bucket) e = R + tid;
      else if (cbase + tid < valid) e = elist[cbase + tid];
      if (e != EINV) {
        const float* rg = rbf + (size_t)e * 6;
        bf16_t t[8] = {(bf16_t)rg[0], (bf16_t)rg[1], (bf16_t)rg[2],
                       (bf16_t)rg[3], (bf16_t)rg[4], (bf16_t)rg[5],
                       (bf16_t)0.f, (bf16_t)0.f};
        *(uint4*)(rbfS + tid * 8) = *(const uint4*)t;
      }
    }
  }
  __syncthreads();                              // barrier 1 (drains vmcnt)

  f32x4 acc[2][4] = {};
  gemm_tile<4, 4>(xA, Wb, mb, nb, l16, q, acc);

  if (br == 0) {
#pragma unroll
    for (int ti = 0; ti < 2; ++ti)
#pragma unroll
      for (int r = 0; r < 4; ++r) {
        const int row = mb + ti * 16 + q * 4 + r;
#pragma unroll
        for (int gl = 0; gl < 2; ++gl) {
          const int col0 = nb + gl * 32 + 2 * l16;
          const float2 b2 = *(const float2*)&biasS[col0];
          *(uint32_t*)&x_ji_out[(size_t)(R + row) * 128 + col0] =
              pack_bf16(silu_f(acc[ti][2 * gl][r] + b2.x),
                        silu_f(acc[ti][2 * gl + 1][r] + b2.y));
        }
      }
    return;
  }

  __syncthreads();                              // barrier 2: xA/Wb reads done

  { // Wdn -> Wb[0:16K] via DMA (in flight during tmp phase)
    const char* ds = wdn_img + (size_t)(br - 1) * 16384;
    char* dd = (char*)Wb;
#pragma unroll
    for (int c = 0; c < 4; ++c) {
      const int off = (c * 4 + wv) * 1024 + lane * 16;
      g2l16(ds + off, dd + off);
    }
  }

  // rbf_p dots + tmp = silu(x@Wkj + b) * rbf_p  -> in place into xA
  float wc[2][2][6];
#pragma unroll
  for (int gl = 0; gl < 2; ++gl)
#pragma unroll
    for (int j = 0; j < 2; ++j) {
      const int col = nb + gl * 32 + 2 * l16 + j;
      bf16x8 w8 = *(const bf16x8*)&wcbS[col * 8];
#pragma unroll
      for (int c = 0; c < 6; ++c) wc[gl][j][c] = (float)w8[c];
    }
#pragma unroll
  for (int ti = 0; ti < 2; ++ti)
#pragma unroll
    for (int r = 0; r < 4; ++r) {
      const int row = mb + ti * 16 + q * 4 + r;
      bf16x8 rv8 = *(const bf16x8*)&rbfS[row * 8];
      float rv[6];
#pragma unroll
      for (int c = 0; c < 6; ++c) rv[c] = (float)rv8[c];
#pragma unroll
      for (int gl = 0; gl < 2; ++gl) {
        const int col0 = nb + gl * 32 + 2 * l16;
        const float2 b2 = *(const float2*)&biasS[col0];
        float p0 = 0.f, p1 = 0.f;
#pragma unroll
        for (int c = 0; c < 6; ++c) {
          p0 += rv[c] * wc[gl][0][c];
          p1 += rv[c] * wc[gl][1][c];
        }
        const float v0 = silu_f(acc[ti][2 * gl][r] + b2.x) * p0;
        const float v1 = silu_f(acc[ti][2 * gl + 1][r] + b2.y) * p1;
        *(uint32_t*)&xA[(row << 7) + ((((col0 >> 3) ^ (row & 15)) << 3) | (col0 & 7))] =
            pack_bf16(v0, v1);
      }
    }
  __syncthreads();                              // barrier 3 (drains Wdn DMA)

  const int nb2 = (wv & 1) * 32;
  f32x4 acc2[2][2] = {};
  gemm_tile<4, 2>(xA, Wb, mb, nb2, l16, q, acc2);
  bf16_t* outp = bucket ? down_bt : down5;
#pragma unroll
  for (int ti = 0; ti < 2; ++ti)
#pragma unroll
    for (int r = 0; r < 4; ++r) {
      const int row = mb + ti * 16 + q * 4 + r;
      int e;
      if (!bucket) e = R + row;
      else {
        if (cbase + row >= valid) continue;
        e = elist[cbase + row];
      }
      const int col0 = nb2 + 2 * l16;
      *(uint32_t*)&outp[(size_t)e * 64 + col0] =
          pack_bf16(silu_f(acc2[ti][0][r]), silu_f(acc2[ti][1][r]));
    }
}

// =====================  K2: per-edge gather (standalone, high occupancy)  ==========
// 8 blocks/CU (12KB LDS). k-loop unrolled by 2 with clamped index; down reads
// select base pointer (down5 vs down_bt) per triplet's branch.
__global__ __launch_bounds__(256, 8)
void gather_kernel(const int* __restrict__ cnt, const int* __restrict__ list,
                   const uint32_t* __restrict__ meta, const float* __restrict__ c8g,
                   const float* __restrict__ Wsbf2, const bf16_t* __restrict__ down5,
                   const bf16_t* __restrict__ down_bt,
                   const float* __restrict__ alpha_p, const int* __restrict__ ovf,
                   float* __restrict__ xkj)
{
  __shared__ float sW2[3072];   // [6][8][64]
  for (int i = threadIdx.x; i < 3072; i += 256) sW2[i] = Wsbf2[i];
  __syncthreads();

  const int e = blockIdx.x * 4 + (threadIdx.x >> 6);
  const int j = threadIdx.x & 63;
  const float alpha = alpha_p[0], oma = 1.f - alpha;
  const float* w5 = &sW2[5 * 512 + j];

  int n = cnt[e];
  if (n > CAP) n = CAP;

  // lane-parallel prefetch: lane k (k<16) holds list/meta entry k
  int tk = 0; uint32_t mk = 0;
  if ((j & 15) < n) {
    tk = list[e * CAP + (j & 15)];
    mk = meta[tk];
  }

  float acc = 0.f;
  const int nn = (n + 1) & ~1;
  for (int k0 = 0; k0 < nn; k0 += 2) {
    const int k1 = (k0 + 1 < n) ? k0 + 1 : n - 1;
    const float sc1 = (k0 + 1 < n) ? 1.f : 0.f;
    const int t0 = __builtin_amdgcn_readfirstlane(__shfl(tk, k0, 64));
    const uint32_t m0 = __builtin_amdgcn_readfirstlane(__shfl(mk, k0, 64));
    const int t1 = __builtin_amdgcn_readfirstlane(__shfl(tk, k1, 64));
    const uint32_t m1 = __builtin_amdgcn_readfirstlane(__shfl(mk, k1, 64));
    const int kj0 = m0 & 0xffff, b0 = m0 >> 16;
    const int kj1 = m1 & 0xffff, b1 = m1 >> 16;
    const bf16_t* pb0 = (b0 == 5) ? down5 : down_bt;
    const bf16_t* pb1 = (b1 == 5) ? down5 : down_bt;
    const float g5a = (float)down5[(size_t)kj0 * 64 + j];
    const float gba = (float)pb0[(size_t)kj0 * 64 + j];
    const float g5b = (float)down5[(size_t)kj1 * 64 + j];
    const float gbb = (float)pb1[(size_t)kj1 * 64 + j];
    const float* cp0 = c8g + (size_t)t0 * 16;
    const float* cp1 = c8g + (size_t)t1 * 16;
    float d5a = 0.f, dba = 0.f, d5b = 0.f, dbb = 0.f;
#pragma unroll
    for (int c = 0; c < 8; ++c) {
      d5a += cp0[c]     * w5[c * 64];
      dba += cp0[8 + c] * sW2[b0 * 512 + c * 64 + j];
      d5b += cp1[c]     * w5[c * 64];
      dbb += cp1[8 + c] * sW2[b1 * 512 + c * 64 + j];
    }
    acc += alpha * g5a * d5a + oma * gba * dba;
    acc += sc1 * (alpha * g5b * d5b + oma * gbb * dbb);
  }

  const int oc = ovf[0];       // normally 0; full correctness fallback
  for (int k = 0; k < oc; ++k) {
    const int ji = ovf[2 + 2 * k + 1];
    if (ji != e) continue;
    const int t = ovf[2 + 2 * k];
    const uint32_t m = meta[t];
    const int kj = m & 0xffff;
    const int b  = m >> 16;
    const bf16_t* pb = (b == 5) ? down5 : down_bt;
    const float g5 = (float)down5[(size_t)kj * 64 + j];
    const float gb = (float)pb[(size_t)kj * 64 + j];
    const float* cp = c8g + (size_t)t * 16;
    float d5 = 0.f, db = 0.f;
#pragma unroll
    for (int c = 0; c < 8; ++c) {
      d5 += cp[c]     * w5[c * 64];
      db += cp[8 + c] * sW2[b * 512 + c * 64 + j];
    }
    acc += alpha * g5 * d5 + oma * gb * db;
  }

  xkj[(size_t)e * 64 + j] = acc;
}

// =====================  K3: fused epilogue chain (R7-proven)  =====================
// LDS 50.2 KB -> 3 blocks/CU: single in-place data buffer, bias double-buffered,
// weights via DMA.
__global__ __launch_bounds__(256, 3)
void epi_kernel(const float* __restrict__ x, const bf16_t* __restrict__ x_ji,
                const float* __restrict__ xkj, const char* __restrict__ pset,
                const float* __restrict__ rb1_b, const float* __restrict__ rb2_b,
                const float* __restrict__ lin_b, const float* __restrict__ ra1_b,
                const float* __restrict__ ra2_b,
                float* __restrict__ out)
{
  __shared__ __align__(16) bf16_t buf[64 * 128];   // 16K, in-place A tile
  __shared__ __align__(16) bf16_t Wb[128 * 128];   // 32K
  __shared__ float biasS[2][128];                  // 1K  -> total 50,176 B

  const int tid = threadIdx.x;
  const int lane = tid & 63, wv = tid >> 6;
  const int q = lane >> 4, l16 = lane & 15;
  const int mb = (wv >> 1) * 32, nb = (wv & 1) * 64;
  const int R = blockIdx.x * 64;

#define DMA_W(SLOT) do {                                                         \
    const char* ps_ = pset + (size_t)(SLOT) * 32768;                             \
    char* wd_ = (char*)Wb;                                                       \
    _Pragma("unroll")                                                            \
    for (int c_ = 0; c_ < 8; ++c_) {                                             \
      const int off_ = (c_ * 4 + wv) * 1024 + lane * 16;                         \
      g2l16(ps_ + off_, wd_ + off_);                                             \
    }                                                                            \
  } while (0)

  stage_x<16>(buf, xkj + (size_t)R * 64, tid);
  DMA_W(0);                                     // W_up image
  __syncthreads();

  f32x4 hreg[2][4];
  { // stage 0: h = x_ji + silu(xkj @ W_up)  -> buf (in place)
    f32x4 acc[2][4] = {};
    gemm_tile<2, 4>(buf, Wb, mb, nb, l16, q, acc);
    __syncthreads();                            // all reads of buf/Wb done
#pragma unroll
    for (int ti = 0; ti < 2; ++ti)
#pragma unroll
      for (int r = 0; r < 4; ++r) {
        const int row = mb + ti * 16 + q * 4 + r;
#pragma unroll
        for (int gl = 0; gl < 2; ++gl) {
          const int col0 = nb + gl * 32 + 2 * l16;
          union { uint32_t u; bf16x2 h; } xj;
          xj.u = *(const uint32_t*)&x_ji[(size_t)(R + row) * 128 + col0];
          const float h0 = (float)xj.h[0] + silu_f(acc[ti][2 * gl][r]);
          const float h1 = (float)xj.h[1] + silu_f(acc[ti][2 * gl + 1][r]);
          hreg[ti][2 * gl][r] = h0;
          hreg[ti][2 * gl + 1][r] = h1;
          *(uint32_t*)&buf[(row << 7) + ((((col0 >> 3) ^ (row & 15)) << 3) | (col0 & 7))] =
              pack_bf16(h0, h1);
        }
      }
    DMA_W(1);
    if (tid < 128) biasS[0][tid] = rb1_b[tid];
    __syncthreads();
  }

// stage K (1..5): gemm from buf, barrier, write phase (bias[(K-1)&1], BODY),
// prefetch next W/bias (K<5), barrier.
#define EPI_STAGE(K, NEXTSLOT, NEXTBIAS, BODY)                                   \
  {                                                                              \
    f32x4 acc[2][4] = {};                                                        \
    gemm_tile<4, 4>(buf, Wb, mb, nb, l16, q, acc);                               \
    __syncthreads();                                                             \
    const float* bs_ = biasS[((K) - 1) & 1];                                     \
    _Pragma("unroll")                                                            \
    for (int ti = 0; ti < 2; ++ti)                                               \
      _Pragma("unroll")                                                          \
      for (int r = 0; r < 4; ++r) {                                              \
        const int row = mb + ti * 16 + q * 4 + r;                                \
        _Pragma("unroll")                                                        \
        for (int gl = 0; gl < 2; ++gl) {                                         \
          const int col0 = nb + gl * 32 + 2 * l16;                               \
          const float2 b2 = *(const float2*)&bs_[col0];                          \
          const float g0 = acc[ti][2 * gl][r] + b2.x;                            \
          const float g1 = acc[ti][2 * gl + 1][r] + b2.y;                        \
          BODY                                                                   \
        }                                                                        \
      }                                                                          \
    if ((K) < 5) {                                                               \
      DMA_W(NEXTSLOT);                                                           \
      if (tid < 128) biasS[(K) & 1][tid] = NEXTBIAS[tid];                        \
      __syncthreads();                                                           \
    }                                                                            \
  }

  // stage 1: u = silu(h @ rb1 + b) -> buf
  EPI_STAGE(1, 2, rb2_b, {
    *(uint32_t*)&buf[(row << 7) + ((((col0 >> 3) ^ (row & 15)) << 3) | (col0 & 7))] =
        pack_bf16(silu_f(g0), silu_f(g1));
  })

  // stage 2: h += silu(u @ rb2 + b) -> buf
  EPI_STAGE(2, 3, lin_b, {
    const float h0 = hreg[ti][2 * gl][r] + silu_f(g0);
    const float h1 = hreg[ti][2 * gl + 1][r] + silu_f(g1);
    hreg[ti][2 * gl][r] = h0; hreg[ti][2 * gl + 1][r] = h1;
    *(uint32_t*)&buf[(row << 7) + ((((col0 >> 3) ^ (row & 15)) << 3) | (col0 & 7))] =
        pack_bf16(h0, h1);
  })

  // stage 3: h = silu(h @ W_lin + b) + x -> buf
  EPI_STAGE(3, 4, ra1_b, {
    const float2 xv = *(const float2*)&x[(size_t)(R + row) * 128 + col0];
    const float h0 = silu_f(g0) + xv.x;
    const float h1 = silu_f(g1) + xv.y;
    hreg[ti][2 * gl][r] = h0; hreg[ti][2 * gl + 1][r] = h1;
    *(uint32_t*)&buf[(row << 7) + ((((col0 >> 3) ^ (row & 15)) << 3) | (col0 & 7))] =
        pack_bf16(h0, h1);
  })

  // stage 4: u = silu(h @ ra1 + b) -> buf
  EPI_STAGE(4, 5, ra2_b, {
    *(uint32_t*)&buf[(row << 7) + ((((col0 >> 3) ^ (row & 15)) << 3) | (col0 & 7))] =
        pack_bf16(silu_f(g0), silu_f(g1));
  })

  // stage 5: out = h + silu(u @ ra2 + b)   (global write only)
  EPI_STAGE(5, 0, ra2_b, {
    float2 o;
    o.x = hreg[ti][2 * gl][r] + silu_f(g0);
    o.y = hreg[ti][2 * gl + 1][r] + silu_f(g1);
    *(float2*)&out[(size_t)(R + row) * 128 + col0] = o;
  })
#undef EPI_STAGE
#undef DMA_W
}

extern "C" void kernel_launch(void* const* d_in, const int* in_sizes, int n_in,
                              void* d_out, int out_size, void* d_ws, size_t ws_size,
                              hipStream_t stream)
{
  (void)in_sizes; (void)n_in; (void)out_size; (void)ws_size;
  const float* x      = (const float*)d_in[0];
  const float* rbf    = (const float*)d_in[1];
  const float* sbf    = (const float*)d_in[2];
  const int*   idx_kj = (const int*)d_in[3];
  const int*   idx_ji = (const int*)d_in[4];
  const int*   bt     = (const int*)d_in[5];
  const float* alpha  = (const float*)d_in[7];
  const float* W_kj   = (const float*)d_in[8];
  const float* b_kj   = (const float*)d_in[9];
  const float* W_rbf1 = (const float*)d_in[10];
  const float* W_rbf2 = (const float*)d_in[11];
  const float* W_sbf1 = (const float*)d_in[12];
  const float* W_sbf2 = (const float*)d_in[13];
  const float* W_down = (const float*)d_in[14];
  const float* W_ji   = (const float*)d_in[15];
  const float* b_ji   = (const float*)d_in[16];
  const float* W_up   = (const float*)d_in[17];
  const float* rb1_w  = (const float*)d_in[18];
  const float* rb1_b  = (const float*)d_in[19];
  const float* rb2_w  = (const float*)d_in[20];
  const float* rb2_b  = (const float*)d_in[21];
  const float* W_lin  = (const float*)d_in[22];
  const float* b_lin  = (const float*)d_in[23];
  const float* ra1_w  = (const float*)d_in[24];
  const float* ra1_b  = (const float*)d_in[25];
  const float* ra2_w  = (const float*)d_in[26];
  const float* ra2_b  = (const float*)d_in[27];

  char* ws = (char*)d_ws;
  bf16_t* down5   = (bf16_t*)(ws);                // E*64*2    =  8,388,608
  bf16_t* down_bt = (bf16_t*)(ws + 8388608);      // E*64*2    =  8,388,608
  bf16_t* x_ji    = (bf16_t*)(ws + 16777216);     // E*128*2   = 16,777,216
  bf16_t* ximg    = (bf16_t*)(ws + 33554432);     // E*128*2   = 16,777,216
  float*  xkj     = (float*) (ws + 50331648);     // E*64*4    = 16,777,216
  char*   wm_img  = ws + 67108864;                // 6*32768   =    196,608
  char*   wdn_img = ws + 67305472;                // 5*16384   =     81,920
  char*   pset    = ws + 67387392;                // 6*32768   =    196,608
  bf16_t* wcb     = (bf16_t*)(ws + 67584000);     // 5*128*8*2 =     10,240
  float*    c8g   = (float*)   (ws + 67594240);   // T*16*4    = 16,777,216
  uint32_t* meta  = (uint32_t*)(ws + 84371456);   // T*4       =  1,048,576
  int*      list  = (int*)     (ws + 85420032);   // E*CAP*4   =  4,194,304
  int*      btlist= (int*)     (ws + 89614336);   // 4*E*4     =  1,048,576
  int*      cnt   = (int*)     (ws + 90662912);   // E*4       =    262,144
  int*      bcnt  = (int*)     (ws + 90925056);   // 4*128     =        512 (padded)
  int*      ovf   = (int*)     (ws + 90925568);   // 8 + 2*T*4 =  2,097,160

  hipMemsetAsync(cnt, 0, 262144 + 512 + 8, stream);  // cnt + bcnt(padded) + ovf[0..1]
  // fused prep + c8 + bt-bucket build (bucket blocks at grid FRONT)
  prep_c8_kernel<<<5491, 256, 0, stream>>>(W_ji, W_kj, W_down, W_up, rb1_w,
                                           rb2_w, W_lin, ra1_w, ra2_w, W_rbf1,
                                           W_rbf2, x, wm_img, wdn_img, pset,
                                           wcb, ximg, sbf, idx_kj, idx_ji, bt,
                                           W_sbf1, c8g, meta, cnt, list, ovf,
                                           btlist, bcnt);
  edge_kernel<<<6144, 256, 0, stream>>>(ximg, rbf, b_kj, b_ji, wm_img, wdn_img,
                                        wcb, btlist, bcnt, x_ji, down5, down_bt);
  gather_kernel<<<E_N / 4, 256, 0, stream>>>(cnt, list, meta, c8g, W_sbf2,
                                             down5, down_bt, alpha, ovf, xkj);
  epi_kernel<<<E_N / 64, 256, 0, stream>>>(x, x_ji, xkj, pset,
                                           rb1_b, rb2_b, b_lin, ra1_b, ra2_b,
                                           (float*)d_out);
}